// Round 19
// baseline (77346.283 us; speedup 1.0000x reference)
//
#include <hip/hip_runtime.h>

#define NB 256
#define NT 512
#define DYNB 160800
#define SCOPE __HIP_MEMORY_SCOPE_AGENT

typedef __attribute__((ext_vector_type(8))) short short8;
typedef __attribute__((ext_vector_type(4))) float f32x4;

__device__ __forceinline__ float b2f(unsigned short s){ return __uint_as_float(((unsigned)s)<<16); }
__device__ __forceinline__ unsigned short f2b(float f){
  unsigned u = __float_as_uint(f);
  return (unsigned short)((u + 0x7FFFu + ((u>>16)&1u))>>16);
}
__device__ __forceinline__ float sigm(float x){ return 1.0f/(1.0f+__expf(-x)); }
__device__ __forceinline__ float tanh_(float x){ float e=__expf(-2.0f*x); return (1.0f-e)/(1.0f+e); }
__device__ __forceinline__ f32x4 mfma16(short8 a, short8 b, f32x4 c){
  return __builtin_amdgcn_mfma_f32_16x16x32_bf16(a,b,c,0,0,0);
}

// device-coherent access (bypass incoherent L1/L2)
__device__ __forceinline__ unsigned long long ldu64(const void* p){
  return __hip_atomic_load((const unsigned long long*)p, __ATOMIC_RELAXED, SCOPE);
}
__device__ __forceinline__ short8 ld8h(const unsigned short* p){
  union{ unsigned long long u[2]; short8 s; } r;
  r.u[0]=ldu64(p); r.u[1]=ldu64(p+4);
  return r.s;
}
__device__ __forceinline__ float2 ld2f(const float* p){
  union{ unsigned long long u; float2 f; } r; r.u=ldu64(p); return r.f;
}
__device__ __forceinline__ float ldf(const float* p){
  return __hip_atomic_load((float*)p, __ATOMIC_RELAXED, SCOPE);
}
__device__ __forceinline__ void stf(float* p, float v){
  __hip_atomic_store(p, v, __ATOMIC_RELAXED, SCOPE);
}
__device__ __forceinline__ void sth(unsigned short* p, unsigned short v){
  __hip_atomic_store(p, v, __ATOMIC_RELAXED, SCOPE);
}

// hierarchical grid barrier: 8 per-XCD arrival counters (128B apart) + root +
// 8 release flags. 32-way RMW contention instead of 256-way; spinners poll
// 8 distinct lines. Correct for ANY block->xcd grouping (groups of 32).
__device__ __forceinline__ void gbar2(unsigned* arrive, unsigned* root, unsigned* release,
                                      int grp, unsigned& ph){
  __syncthreads();
  if (threadIdx.x==0){
    ph += 1;
    asm volatile("s_waitcnt vmcnt(0)" ::: "memory");
    unsigned old = __hip_atomic_fetch_add(&arrive[grp*32], 1u, __ATOMIC_RELAXED, SCOPE);
    if (old == ph*32u - 1u){
      __hip_atomic_fetch_add(root, 1u, __ATOMIC_RELAXED, SCOPE);
      while (__hip_atomic_load(root, __ATOMIC_RELAXED, SCOPE) < ph*8u){
        __builtin_amdgcn_s_sleep(1);
      }
      __hip_atomic_store(&release[grp*32], ph, __ATOMIC_RELAXED, SCOPE);
    } else {
      while (__hip_atomic_load(&release[grp*32], __ATOMIC_RELAXED, SCOPE) < ph){
        __builtin_amdgcn_s_sleep(1);
      }
    }
  }
  __syncthreads();
}

// ---------------- precompute kernels ----------------

__global__ void maskdet_k(const unsigned* __restrict__ m32, int* __restrict__ flag){
  __shared__ int ok;
  if (threadIdx.x==0) ok = 1;
  __syncthreads();
  for (int i=threadIdx.x; i<4096; i+=256){
    if (m32[i] > 1u) ok = 0;
  }
  __syncthreads();
  if (threadIdx.x==0) *flag = ok;
}

__global__ void xin2bf_k(const float* __restrict__ xin, unsigned short* __restrict__ xinh){
  size_t i = (size_t)blockIdx.x*256 + threadIdx.x;
  if (i < (size_t)64*256*512) xinh[i] = f2b(xin[i]);
}

__global__ void prenet_k(const float* __restrict__ target, const float* __restrict__ W1, const float* __restrict__ b1,
                         const float* __restrict__ W2, const float* __restrict__ b2,
                         unsigned short* __restrict__ xbh){
  int t = blockIdx.x;
  int tid = threadIdx.x;
  __shared__ float stgt[64][80];
  __shared__ float smid[64][256];
  for(int i=tid;i<64*80;i+=256){
    int b=i/80, c=i%80;
    stgt[b][c] = (t==0)?0.f : target[((size_t)b*80+c)*400 + (t-1)];
  }
  __syncthreads();
  {
    float w1r[80];
    #pragma unroll
    for(int c=0;c<80;c++) w1r[c] = W1[tid*80+c];
    float bb1 = b1[tid];
    for(int b0=0;b0<64;b0+=16){
      float acc[16];
      #pragma unroll
      for(int i=0;i<16;i++) acc[i]=0.f;
      for(int c=0;c<80;c++){
        float wv=w1r[c];
        #pragma unroll
        for(int i=0;i<16;i++) acc[i] += wv*stgt[b0+i][c];
      }
      #pragma unroll
      for(int i=0;i<16;i++) smid[b0+i][tid] = fmaxf(acc[i]+bb1, 0.f);
    }
  }
  __syncthreads();
  {
    float bb2 = b2[tid];
    for(int b0=0;b0<64;b0+=16){
      float acc[16];
      #pragma unroll
      for(int i=0;i<16;i++) acc[i]=0.f;
      for(int c=0;c<256;c++){
        float wv=W2[tid*256+c];
        #pragma unroll
        for(int i=0;i<16;i++) acc[i] += wv*smid[b0+i][c];
      }
      #pragma unroll
      for(int i=0;i<16;i++){
        float v = fmaxf(acc[i]+bb2,0.f);
        xbh[((size_t)t*64 + b0+i)*256 + tid] = f2b(v);
      }
    }
  }
}

__global__ void keyproj_k(const float* __restrict__ xin, const float* __restrict__ Wk, unsigned short* __restrict__ keypT){
  int b = blockIdx.x>>4; int t0=(blockIdx.x&15)*16; int m=threadIdx.x; // 128 threads
  __shared__ float sx[16][512];
  for(int i=m;i<16*512;i+=128){ int tt=i>>9, f=i&511; sx[tt][f]=xin[((size_t)b*256+t0+tt)*512+f]; }
  __syncthreads();
  float s[16];
  #pragma unroll
  for(int i=0;i<16;i++) s[i]=0.f;
  for(int f=0;f<512;f++){
    float wv = Wk[m*512+f];
    #pragma unroll
    for(int i=0;i<16;i++) s[i]+=sx[i][f]*wv;
  }
  #pragma unroll
  for(int i=0;i<16;i++) keypT[((size_t)b*128+m)*256 + t0+i] = f2b(s[i]);
}

__global__ void prep_k(const float* bih1,const float* bhh1,const float* bih2,const float* bhh2,
                       const float* Wloc, float* bsum1,float* bsum2, unsigned short* WlocH){
  int i0 = blockIdx.x*blockDim.x + threadIdx.x;
  int n = gridDim.x*blockDim.x;
  for(int k=i0;k<4096;k+=n){
    bsum1[k]=bih1[k]+bhh1[k];
    bsum2[k]=bih2[k]+bhh2[k];
    WlocH[k]=f2b(Wloc[k]);
  }
}

__global__ void perm_k(const float* __restrict__ Wih1, const float* __restrict__ Whh1,
                       const float* __restrict__ Wih2, const float* __restrict__ Whh2,
                       unsigned short* __restrict__ Wp1h, unsigned short* __restrict__ Wp2h){
  size_t i0 = (size_t)blockIdx.x*blockDim.x + threadIdx.x;
  size_t n  = (size_t)gridDim.x*blockDim.x;
  const size_t N1 = (size_t)256*56*512;
  for(size_t idx=i0; idx<N1; idx+=n){
    int beta = (int)(idx/28672);
    int r = (int)(idx%28672);
    int kt = r/512;
    int l  = (r>>3)&63;
    int i8 = r&7;
    int c = l&15, cci = l>>4;
    int k = kt*32 + cci*8 + i8;
    int rowp = (c>>2)*1024 + beta*4 + (c&3);
    float v = (k<768)? Wih1[(size_t)rowp*768 + k] : Whh1[(size_t)rowp*1024 + (k-768)];
    Wp1h[idx] = f2b(v);
  }
  const size_t N2 = (size_t)256*80*512;
  for(size_t idx=i0; idx<N2; idx+=n){
    int beta = (int)(idx/40960);
    int r = (int)(idx%40960);
    int kt = r/512;
    int l  = (r>>3)&63;
    int i8 = r&7;
    int c = l&15, cci = l>>4;
    int k = kt*32 + cci*8 + i8;
    int rowp = (c>>2)*1024 + beta*4 + (c&3);
    float v = (k<1536)? Wih2[(size_t)rowp*1536 + k] : Whh2[(size_t)rowp*1024 + (k-1536)];
    Wp2h[idx] = f2b(v);
  }
}

// ---------------- the scan (persistent; 2 barriers/step; hierarchical barrier) ----------------

struct SArgs {
  const float* loc_conv; const float* v_att; const float* bout;
  const float* Wq; const float* Wout;
  const unsigned short* keypT; const unsigned short* xinh; const unsigned short* WlocH;
  const unsigned short* xbh;
  const unsigned short* Wp1h; const unsigned short* Wp2h;
  const float* bsum1; const float* bsum2;
  const unsigned char* mask8; const int* mask32; const int* mflag;
  unsigned short* h1h; float* h1f;
  unsigned short* h2h; float* h2f;
  unsigned short* ctxh; float* ctxf;
  float* c1; float* c2;
  float* aw; float* awc; float* locT;
  unsigned* arrive; unsigned* root; unsigned* release;
  float* outp; float* wout;
};

__global__ void __launch_bounds__(NT) scan_kernel(SArgs a){
  extern __shared__ char dynsm[];
  unsigned short* Lw1 = (unsigned short*)dynsm;             // 28672 bf16
  unsigned short* Lw2 = (unsigned short*)(dynsm + 57344);   // 40960 bf16
  float* gsc1 = (float*)(dynsm + 139264);                   // [64][16]
  float* gsc2 = (float*)(dynsm + 143360);                   // [64][16]
  float* sA   = (float*)(dynsm + 147456);                   // 3072 f32
  float* sq   = (float*)(dynsm + 159744);                   // 128 f32
  float* sv   = (float*)(dynsm + 160256);                   // 128 f32 (+8 red)
  float* red  = sv + 128;

  const int beta = ((blockIdx.x & 7) << 5) | (blockIdx.x >> 3);  // XCD-chunked
  const int grp  = blockIdx.x & 7;                               // barrier group
  const int tid = threadIdx.x;
  const int wav = tid>>6;
  const int lan = tid&63;

  const int cc  = lan>>4;
  const int b4  = beta>>2;
  const int q4  = beta&3;
  unsigned ph = 0;

  {
    const short8* g1 = (const short8*)(a.Wp1h + (size_t)beta*28672);
    short8* l1 = (short8*)Lw1;
    for (int i=tid; i<3584; i+=NT) l1[i] = g1[i];
    const short8* g2 = (const short8*)(a.Wp2h + (size_t)beta*40960);
    short8* l2 = (short8*)Lw2;
    for (int i=tid; i<5120; i+=NT) l2[i] = g2[i];
  }

  // mask for e-computation: thread pair (tid>>1) owns t
  bool mvE;
  {
    int t = tid>>1;
    mvE = (a.mflag[0] ? (a.mask32[b4*256+t] != 0) : (a.mask8[b4*256+t] != 0));
  }
  __syncthreads();

  for (int tau=0; tau<=400; ++tau){
    const int p = tau&1;
    // ========== Phase A: LSTM1 (waves 0-3) || LSTM2 (waves 4-7); gates; locT ==========
    if (tau<400 && wav<4){
      const int row = wav*16 + (lan&15);
      f32x4 A0={0.f,0.f,0.f,0.f};
      const unsigned short* wh = Lw1 + lan*8;
      {
        const unsigned short* xh = a.xbh + ((size_t)tau*64 + row)*256 + cc*8;
        #pragma unroll
        for(int kt=0;kt<8;kt++)
          A0=mfma16(*(const short8*)(xh+kt*32), *(const short8*)(wh+kt*512), A0);
      }
      {
        const unsigned short* xh = a.ctxh + row*512 + cc*8;
        #pragma unroll 8
        for(int kt=8;kt<24;kt++)
          A0=mfma16(ld8h(xh+(kt-8)*32), *(const short8*)(wh+kt*512), A0);
      }
      {
        const unsigned short* xh = a.h1h + (size_t)(p^1)*65536 + row*1024 + cc*8;
        #pragma unroll 8
        for(int kt=24;kt<56;kt++)
          A0=mfma16(ld8h(xh+(kt-24)*32), *(const short8*)(wh+kt*512), A0);
      }
      #pragma unroll
      for(int r=0;r<4;r++) gsc1[(wav*16 + cc*4 + r)*16 + (lan&15)] = A0[r];
    }
    if (tau>0 && wav>=4){
      const int wv2 = wav-4;
      const int row = wv2*16 + (lan&15);
      f32x4 A0={0.f,0.f,0.f,0.f};
      const unsigned short* wh = Lw2 + lan*8;
      {
        const unsigned short* xh = a.h1h + (size_t)(p^1)*65536 + row*1024 + cc*8;
        #pragma unroll 8
        for(int kt=0;kt<32;kt++)
          A0=mfma16(ld8h(xh+kt*32), *(const short8*)(wh+kt*512), A0);
      }
      {
        const unsigned short* xh = a.ctxh + row*512 + cc*8;
        #pragma unroll 8
        for(int kt=32;kt<48;kt++)
          A0=mfma16(ld8h(xh+(kt-32)*32), *(const short8*)(wh+kt*512), A0);
      }
      {
        const unsigned short* xh = a.h2h + (size_t)p*65536 + row*1024 + cc*8;
        #pragma unroll 8
        for(int kt=48;kt<80;kt++)
          A0=mfma16(ld8h(xh+(kt-48)*32), *(const short8*)(wh+kt*512), A0);
      }
      #pragma unroll
      for(int r=0;r<4;r++) gsc2[(wv2*16 + cc*4 + r)*16 + (lan&15)] = A0[r];
    }
    __syncthreads();
    if (tau<400 && tid<256){
      int m = tid>>2, j = tid&3, u = beta*4+j;
      float gi = gsc1[m*16+0+j]  + a.bsum1[0*1024+u];
      float gf = gsc1[m*16+4+j]  + a.bsum1[1*1024+u];
      float gg = gsc1[m*16+8+j]  + a.bsum1[2*1024+u];
      float go = gsc1[m*16+12+j] + a.bsum1[3*1024+u];
      float cp = a.c1[m*1024+u];
      float cn = sigm(gf)*cp + sigm(gi)*tanh_(gg);
      a.c1[m*1024+u] = cn;
      float hn = sigm(go)*tanh_(cn);
      stf(a.h1f + m*1024+u, hn);
      sth(a.h1h + (size_t)p*65536 + m*1024 + u, f2b(hn));
    }
    if (tau>0 && tid>=256){
      int t2 = tid-256;
      int m = t2>>2, j = t2&3, u = beta*4+j;
      float gi = gsc2[m*16+0+j]  + a.bsum2[0*1024+u];
      float gf = gsc2[m*16+4+j]  + a.bsum2[1*1024+u];
      float gg = gsc2[m*16+8+j]  + a.bsum2[2*1024+u];
      float go = gsc2[m*16+12+j] + a.bsum2[3*1024+u];
      float cp = a.c2[m*1024+u];
      float cn = sigm(gf)*cp + sigm(gi)*tanh_(gg);
      a.c2[m*1024+u] = cn;
      float hn = sigm(go)*tanh_(cn);
      stf(a.h2f + m*1024+u, hn);
      sth(a.h2h + (size_t)(p^1)*65536 + m*1024 + u, f2b(hn));
    }
    if (tau<400){
      if (tid<128){
        float2 v = ld2f(a.aw + b4*256 + tid*2);
        sA[tid*2]=v.x; sA[tid*2+1]=v.y;
        float2 w2 = ld2f(a.awc + b4*256 + tid*2);
        sA[256+tid*2]=w2.x; sA[257+tid*2]=w2.y;
      }
      for(int i=tid;i<1984;i+=NT) sA[512+i] = a.loc_conv[i];
    }
    __syncthreads();
    if (tau<400){
      const int t0 = q4*64;
      #pragma unroll
      for(int jj=0;jj<4;jj++){
        int o = tid*4+jj;
        int f = o>>6, tl = o&63, t = t0+tl;
        float s = 0.f;
        #pragma unroll
        for(int c=0;c<2;c++){
          const float* kw = &sA[512 + (f*2+c)*31];
          const float* wv = &sA[c*256];
          for(int k=0;k<31;k++){
            int tt = t + k - 15;
            if (tt>=0 && tt<256) s += wv[tt]*kw[k];
          }
        }
        stf(a.locT + (size_t)b4*8192 + f*256 + t, s);
      }
    }
    gbar2(a.arrive, a.root, a.release, grp, ph);
    // ========== Phase B': q4==0 -> full attention(tau); q4>0 -> out-proj(tau-1) ==========
    if (q4==0){
      if (tau<400){
        // stage h1f[b4]
        for(int i=tid*2;i<1024;i+=NT*2){
          float2 v = ld2f(a.h1f + b4*1024 + i);
          sA[i]=v.x; sA[i+1]=v.y;
        }
        if (tid<128) sv[tid] = a.v_att[tid];
        __syncthreads();
        // q[m] for all 128 m: 4 threads per m
        {
          int m = tid>>2, sg = tid&3;
          const float* wq = a.Wq + (size_t)m*1024;
          float s=0.f;
          #pragma unroll 8
          for(int i=0;i<256;i++) s += sA[sg + i*4]*wq[sg + i*4];
          s += __shfl_xor(s,1); s += __shfl_xor(s,2);
          if (sg==0) sq[m] = s;
        }
        __syncthreads();
        // Wloc bf16 into sA bytes [0,8192)
        {
          unsigned short* wl = (unsigned short*)sA;
          for(int i=tid;i<4096;i+=NT) wl[i] = a.WlocH[i];
        }
        __syncthreads();
        // e[t]: thread pair (2 threads per t), 64 mm each
        {
          int t = tid>>1, half = tid&1;
          const unsigned short* wl = (const unsigned short*)sA;
          float lc[32];
          const float* lb = a.locT + (size_t)b4*8192 + t;
          #pragma unroll
          for(int f=0;f<32;f++) lc[f] = ldf(lb + f*256);
          const unsigned short* kb = a.keypT + ((size_t)b4*128 + half*64)*256 + t;
          float acc=0.f;
          for(int mm0=0;mm0<64;mm0++){
            int mm = half*64+mm0;
            float lf=0.f;
            #pragma unroll
            for(int f=0;f<32;f++) lf += lc[f]*b2f(wl[mm*32+f]);
            acc += tanh_(sq[mm] + b2f(kb[(size_t)mm0*256]) + lf)*sv[mm];
          }
          acc += __shfl_xor(acc,1);
          if (half==0) sA[2048+t] = mvE ? acc : -1e9f;
        }
        __syncthreads();
        // softmax over t (tid<256)
        if (tid<256){
          float e = sA[2048+tid];
          float mx = e;
          #pragma unroll
          for(int off=1;off<64;off<<=1) mx = fmaxf(mx, __shfl_xor(mx,off));
          if (lan==0) red[wav] = mx;
        }
        __syncthreads();
        if (tid<256){
          float e = sA[2048+tid];
          float mx = fmaxf(fmaxf(red[0],red[1]), fmaxf(red[2],red[3]));
          float pe = __expf(e-mx);
          float sm = pe;
          #pragma unroll
          for(int off=1;off<64;off<<=1) sm += __shfl_xor(sm,off);
          if (lan==0) red[4+wav] = sm;
          __syncthreads();
          sm = red[4]+red[5]+red[6]+red[7];
          float awt = pe/sm;
          sA[2304+tid] = awt;
          stf(a.aw + b4*256+tid, awt);
          stf(a.awc + b4*256+tid, ldf(a.awc + b4*256+tid) + awt);
          a.wout[(size_t)b4*102400 + (size_t)tid*400 + tau] = awt;
        } else {
          __syncthreads();
        }
        __syncthreads();
        // ctx[f] for all 512 f: one thread per f, sum over 256 t
        {
          int f = tid;
          const unsigned short* xp = a.xinh + (size_t)b4*256*512 + f;
          float s=0.f;
          for(int t=0;t<256;t++) s += sA[2304+t]*b2f(xp[(size_t)t*512]);
          stf(a.ctxf + b4*512 + f, s);
          sth(a.ctxh + b4*512 + f, f2b(s));
        }
      }
    } else {
      if (tau>0){
        // out-projection for tau-1: q4 in {1,2,3} -> nm ranges 0-26,27-53,54-79
        for(int i=tid*2;i<1024;i+=NT*2){
          float2 v = ld2f(a.h2f + b4*1024 + i);
          sA[i]=v.x; sA[i+1]=v.y;
        }
        if (tid<256){
          float2 v = ld2f(a.ctxf + b4*512 + tid*2);
          sA[1024+tid*2]=v.x; sA[1025+tid*2]=v.y;
        }
        __syncthreads();
        int base = (q4-1)*27;
        int cnt = (q4==3)? 26 : 27;
        int nl = tid>>3, sg = tid&7;
        if (nl < cnt){
          int nm = base + nl;
          const float* wo = a.Wout + (size_t)nm*1536;
          float s=0.f;
          #pragma unroll 8
          for(int i=0;i<192;i++) s += sA[sg + i*8]*wo[sg + i*8];
          s += __shfl_xor(s,1); s += __shfl_xor(s,2); s += __shfl_xor(s,4);
          if (sg==0) a.outp[(size_t)b4*32000 + nm*400 + (tau-1)] = s + a.bout[nm];
        }
      }
    }
    if (tau==400) break;
    gbar2(a.arrive, a.root, a.release, grp, ph);
  }
}

extern "C" void kernel_launch(void* const* d_in, const int* in_sizes, int n_in,
                              void* d_out, int out_size, void* d_ws, size_t ws_size,
                              hipStream_t stream){
  (void)in_sizes; (void)n_in; (void)out_size; (void)ws_size;
  const float* xin   = (const float*)d_in[0];
  const float* target= (const float*)d_in[2];
  const float* Wpre1 = (const float*)d_in[3];
  const float* bpre1 = (const float*)d_in[4];
  const float* Wpre2 = (const float*)d_in[5];
  const float* bpre2 = (const float*)d_in[6];
  const float* Wq    = (const float*)d_in[7];
  const float* Wk    = (const float*)d_in[8];
  const float* loc_conv = (const float*)d_in[9];
  const float* Wloc  = (const float*)d_in[10];
  const float* v_att = (const float*)d_in[11];
  const float* Wih1  = (const float*)d_in[12];
  const float* Whh1  = (const float*)d_in[13];
  const float* bih1  = (const float*)d_in[14];
  const float* bhh1  = (const float*)d_in[15];
  const float* Wih2  = (const float*)d_in[16];
  const float* Whh2  = (const float*)d_in[17];
  const float* bih2  = (const float*)d_in[18];
  const float* bhh2  = (const float*)d_in[19];
  const float* Wout  = (const float*)d_in[20];
  const float* boutp = (const float*)d_in[21];

  char* w = (char*)d_ws;
  auto carve=[&](size_t bytes)->void*{ void* r=(void*)w; w += (bytes+255)&~(size_t)255; return r; };
  // state region (zeroed every launch) — must stay first & contiguous
  unsigned short* h1h = (unsigned short*)carve((size_t)2*64*1024*2);
  unsigned short* h2h = (unsigned short*)carve((size_t)2*64*1024*2);
  unsigned short* ctxh= (unsigned short*)carve((size_t)64*512*2);
  float* h1f = (float*)carve((size_t)64*1024*4);
  float* h2f = (float*)carve((size_t)64*1024*4);
  float* ctxf= (float*)carve((size_t)64*512*4);
  float* c1  = (float*)carve((size_t)64*1024*4);
  float* c2  = (float*)carve((size_t)64*1024*4);
  float* aw  = (float*)carve((size_t)64*256*4);
  float* awc = (float*)carve((size_t)64*256*4);
  unsigned* arrive  = (unsigned*)carve(1024);   // 8 counters, 128B apart
  unsigned* rootc   = (unsigned*)carve(256);
  unsigned* release = (unsigned*)carve(1024);
  int* mflag = (int*)carve(256);
  size_t state_bytes = (size_t)(w - (char*)d_ws);
  float* locT = (float*)carve((size_t)64*32*256*4);
  unsigned short* keypT = (unsigned short*)carve((size_t)64*128*256*2);
  unsigned short* xinh  = (unsigned short*)carve((size_t)64*256*512*2);
  unsigned short* xbh = (unsigned short*)carve((size_t)400*64*256*2);
  float* bsum1 = (float*)carve((size_t)4096*4);
  float* bsum2 = (float*)carve((size_t)4096*4);
  unsigned short* WlocH = (unsigned short*)carve((size_t)4096*2);
  unsigned short* Wp1h = (unsigned short*)carve((size_t)256*56*512*2);
  unsigned short* Wp2h = (unsigned short*)carve((size_t)256*80*512*2);

  hipMemsetAsync(d_ws, 0, state_bytes, stream);
  maskdet_k<<<1, 256, 0, stream>>>((const unsigned*)d_in[1], mflag);
  xin2bf_k<<<32768, 256, 0, stream>>>(xin, xinh);
  prenet_k<<<400, 256, 0, stream>>>(target, Wpre1, bpre1, Wpre2, bpre2, xbh);
  keyproj_k<<<1024, 128, 0, stream>>>(xin, Wk, keypT);
  prep_k<<<16, 256, 0, stream>>>(bih1,bhh1,bih2,bhh2,Wloc,bsum1,bsum2,WlocH);
  perm_k<<<2048, 256, 0, stream>>>(Wih1,Whh1,Wih2,Whh2,Wp1h,Wp2h);

  SArgs a;
  a.loc_conv=loc_conv; a.v_att=v_att; a.bout=boutp;
  a.Wq=Wq; a.Wout=Wout;
  a.keypT=keypT; a.xinh=xinh; a.WlocH=WlocH; a.xbh=xbh;
  a.Wp1h=Wp1h; a.Wp2h=Wp2h;
  a.bsum1=bsum1; a.bsum2=bsum2;
  a.mask8=(const unsigned char*)d_in[1]; a.mask32=(const int*)d_in[1]; a.mflag=mflag;
  a.h1h=h1h; a.h1f=h1f;
  a.h2h=h2h; a.h2f=h2f;
  a.ctxh=ctxh; a.ctxf=ctxf;
  a.c1=c1; a.c2=c2;
  a.aw=aw; a.awc=awc; a.locT=locT;
  a.arrive=arrive; a.root=rootc; a.release=release;
  a.outp=(float*)d_out; a.wout=(float*)d_out + (size_t)64*80*400;

  hipFuncSetAttribute((const void*)scan_kernel, hipFuncAttributeMaxDynamicSharedMemorySize, DYNB);
  scan_kernel<<<dim3(NB), dim3(NT), DYNB, stream>>>(a);
}

// Round 20
// 51286.200 us; speedup vs baseline: 1.5081x; 1.5081x over previous
//
#include <hip/hip_runtime.h>

#define NB 256
#define NT 512
#define DYNB 158496
#define SCOPE __HIP_MEMORY_SCOPE_AGENT

typedef __attribute__((ext_vector_type(8))) short short8;
typedef __attribute__((ext_vector_type(4))) float f32x4;

__device__ __forceinline__ float b2f(unsigned short s){ return __uint_as_float(((unsigned)s)<<16); }
__device__ __forceinline__ unsigned short f2b(float f){
  unsigned u = __float_as_uint(f);
  return (unsigned short)((u + 0x7FFFu + ((u>>16)&1u))>>16);
}
__device__ __forceinline__ float sigm(float x){ return 1.0f/(1.0f+__expf(-x)); }
__device__ __forceinline__ float tanh_(float x){ float e=__expf(-2.0f*x); return (1.0f-e)/(1.0f+e); }
__device__ __forceinline__ f32x4 mfma16(short8 a, short8 b, f32x4 c){
  return __builtin_amdgcn_mfma_f32_16x16x32_bf16(a,b,c,0,0,0);
}

// device-coherent access (bypass incoherent L1/L2)
__device__ __forceinline__ unsigned long long ldu64(const void* p){
  return __hip_atomic_load((const unsigned long long*)p, __ATOMIC_RELAXED, SCOPE);
}
__device__ __forceinline__ short8 ld8h(const unsigned short* p){
  union{ unsigned long long u[2]; short8 s; } r;
  r.u[0]=ldu64(p); r.u[1]=ldu64(p+4);
  return r.s;
}
__device__ __forceinline__ float2 ld2f(const float* p){
  union{ unsigned long long u; float2 f; } r; r.u=ldu64(p); return r.f;
}
__device__ __forceinline__ float ldf(const float* p){
  return __hip_atomic_load((float*)p, __ATOMIC_RELAXED, SCOPE);
}
__device__ __forceinline__ void stf(float* p, float v){
  __hip_atomic_store(p, v, __ATOMIC_RELAXED, SCOPE);
}
__device__ __forceinline__ void sth(unsigned short* p, unsigned short v){
  __hip_atomic_store(p, v, __ATOMIC_RELAXED, SCOPE);
}

// hierarchical grid barrier: 8 per-XCD arrival counters (128B apart) + root +
// 8 release flags. 32-way RMW contention (x8 parallel) instead of 256-way on
// one line; spinners poll 8 distinct lines.
__device__ __forceinline__ void gbar2(unsigned* arrive, unsigned* root, unsigned* release,
                                      int grp, unsigned& ph){
  __syncthreads();
  if (threadIdx.x==0){
    ph += 1;
    asm volatile("s_waitcnt vmcnt(0)" ::: "memory");
    unsigned old = __hip_atomic_fetch_add(&arrive[grp*32], 1u, __ATOMIC_RELAXED, SCOPE);
    if (old == ph*32u - 1u){
      __hip_atomic_fetch_add(root, 1u, __ATOMIC_RELAXED, SCOPE);
      while (__hip_atomic_load(root, __ATOMIC_RELAXED, SCOPE) < ph*8u){
        __builtin_amdgcn_s_sleep(1);
      }
      __hip_atomic_store(&release[grp*32], ph, __ATOMIC_RELAXED, SCOPE);
    } else {
      while (__hip_atomic_load(&release[grp*32], __ATOMIC_RELAXED, SCOPE) < ph){
        __builtin_amdgcn_s_sleep(1);
      }
    }
  }
  __syncthreads();
}

// ---------------- precompute kernels ----------------

__global__ void maskdet_k(const unsigned* __restrict__ m32, int* __restrict__ flag){
  __shared__ int ok;
  if (threadIdx.x==0) ok = 1;
  __syncthreads();
  for (int i=threadIdx.x; i<4096; i+=256){
    if (m32[i] > 1u) ok = 0;
  }
  __syncthreads();
  if (threadIdx.x==0) *flag = ok;
}

__global__ void xin2bf_k(const float* __restrict__ xin, unsigned short* __restrict__ xinh){
  size_t i = (size_t)blockIdx.x*256 + threadIdx.x;
  if (i < (size_t)64*256*512) xinh[i] = f2b(xin[i]);
}

__global__ void prenet_k(const float* __restrict__ target, const float* __restrict__ W1, const float* __restrict__ b1,
                         const float* __restrict__ W2, const float* __restrict__ b2,
                         unsigned short* __restrict__ xbh){
  int t = blockIdx.x;
  int tid = threadIdx.x;
  __shared__ float stgt[64][80];
  __shared__ float smid[64][256];
  for(int i=tid;i<64*80;i+=256){
    int b=i/80, c=i%80;
    stgt[b][c] = (t==0)?0.f : target[((size_t)b*80+c)*400 + (t-1)];
  }
  __syncthreads();
  {
    float w1r[80];
    #pragma unroll
    for(int c=0;c<80;c++) w1r[c] = W1[tid*80+c];
    float bb1 = b1[tid];
    for(int b0=0;b0<64;b0+=16){
      float acc[16];
      #pragma unroll
      for(int i=0;i<16;i++) acc[i]=0.f;
      for(int c=0;c<80;c++){
        float wv=w1r[c];
        #pragma unroll
        for(int i=0;i<16;i++) acc[i] += wv*stgt[b0+i][c];
      }
      #pragma unroll
      for(int i=0;i<16;i++) smid[b0+i][tid] = fmaxf(acc[i]+bb1, 0.f);
    }
  }
  __syncthreads();
  {
    float bb2 = b2[tid];
    for(int b0=0;b0<64;b0+=16){
      float acc[16];
      #pragma unroll
      for(int i=0;i<16;i++) acc[i]=0.f;
      for(int c=0;c<256;c++){
        float wv=W2[tid*256+c];
        #pragma unroll
        for(int i=0;i<16;i++) acc[i] += wv*smid[b0+i][c];
      }
      #pragma unroll
      for(int i=0;i<16;i++){
        float v = fmaxf(acc[i]+bb2,0.f);
        xbh[((size_t)t*64 + b0+i)*256 + tid] = f2b(v);
      }
    }
  }
}

// writes keypT[b][m][t] as bf16 (transposed + halved)
__global__ void keyproj_k(const float* __restrict__ xin, const float* __restrict__ Wk, unsigned short* __restrict__ keypT){
  int b = blockIdx.x>>4; int t0=(blockIdx.x&15)*16; int m=threadIdx.x; // 128 threads
  __shared__ float sx[16][512];
  for(int i=m;i<16*512;i+=128){ int tt=i>>9, f=i&511; sx[tt][f]=xin[((size_t)b*256+t0+tt)*512+f]; }
  __syncthreads();
  float s[16];
  #pragma unroll
  for(int i=0;i<16;i++) s[i]=0.f;
  for(int f=0;f<512;f++){
    float wv = Wk[m*512+f];
    #pragma unroll
    for(int i=0;i<16;i++) s[i]+=sx[i][f]*wv;
  }
  #pragma unroll
  for(int i=0;i<16;i++) keypT[((size_t)b*128+m)*256 + t0+i] = f2b(s[i]);
}

__global__ void prep_k(const float* bih1,const float* bhh1,const float* bih2,const float* bhh2,
                       float* bsum1,float* bsum2){
  int i0 = blockIdx.x*blockDim.x + threadIdx.x;
  int n = gridDim.x*blockDim.x;
  for(int k=i0;k<4096;k+=n){ bsum1[k]=bih1[k]+bhh1[k]; bsum2[k]=bih2[k]+bhh2[k]; }
}

__global__ void perm_k(const float* __restrict__ Wih1, const float* __restrict__ Whh1,
                       const float* __restrict__ Wih2, const float* __restrict__ Whh2,
                       unsigned short* __restrict__ Wp1h, unsigned short* __restrict__ Wp2h){
  size_t i0 = (size_t)blockIdx.x*blockDim.x + threadIdx.x;
  size_t n  = (size_t)gridDim.x*blockDim.x;
  const size_t N1 = (size_t)256*56*512;
  for(size_t idx=i0; idx<N1; idx+=n){
    int beta = (int)(idx/28672);
    int r = (int)(idx%28672);
    int kt = r/512;
    int l  = (r>>3)&63;
    int i8 = r&7;
    int c = l&15, cci = l>>4;
    int k = kt*32 + cci*8 + i8;
    int rowp = (c>>2)*1024 + beta*4 + (c&3);
    float v = (k<768)? Wih1[(size_t)rowp*768 + k] : Whh1[(size_t)rowp*1024 + (k-768)];
    Wp1h[idx] = f2b(v);
  }
  const size_t N2 = (size_t)256*80*512;
  for(size_t idx=i0; idx<N2; idx+=n){
    int beta = (int)(idx/40960);
    int r = (int)(idx%40960);
    int kt = r/512;
    int l  = (r>>3)&63;
    int i8 = r&7;
    int c = l&15, cci = l>>4;
    int k = kt*32 + cci*8 + i8;
    int rowp = (c>>2)*1024 + beta*4 + (c&3);
    float v = (k<1536)? Wih2[(size_t)rowp*1536 + k] : Whh2[(size_t)rowp*1024 + (k-1536)];
    Wp2h[idx] = f2b(v);
  }
}

// ---------------- the scan (R18 structure + hierarchical barrier) ----------------

struct SArgs {
  const float* xin; const float* loc_conv; const float* Wloc; const float* v_att; const float* bout;
  const float* Wq; const float* Wout;
  const unsigned short* keypT; const unsigned short* xinh;
  const unsigned short* xbh;
  const unsigned short* Wp1h; const unsigned short* Wp2h;
  const float* bsum1; const float* bsum2;
  const unsigned char* mask8; const int* mask32; const int* mflag;
  unsigned short* h1h; float* h1f;
  unsigned short* h2h; float* h2f;
  unsigned short* ctxh; float* ctxf;
  float* c1; float* c2;
  float* aw; float* awc; float* eP; float* locT;
  unsigned* arrive; unsigned* root; unsigned* release;
  float* outp; float* wout;
};

__global__ void __launch_bounds__(NT) scan_kernel(SArgs a){
  extern __shared__ char dynsm[];
  unsigned short* Lw1 = (unsigned short*)dynsm;             // 28672
  unsigned short* Lw2 = (unsigned short*)(dynsm + 57344);   // 40960
  float* gsc1 = (float*)(dynsm + 139264);                   // [64][17]
  float* gsc2 = (float*)(dynsm + 143616);                   // [64][17]
  float* sA   = (float*)(dynsm + 147968);                   // [2560]
  float* sq   = (float*)(dynsm + 158208);                   // [32]
  float* sv   = (float*)(dynsm + 158336);                   // [32]
  float* red  = (float*)(dynsm + 158464);                   // [8]

  // XCD-aware swizzle (R18): each XCD hosts 32 consecutive logical betas.
  const int beta = ((blockIdx.x & 7) << 5) | (blockIdx.x >> 3);
  const int grp  = blockIdx.x & 7;
  const int tid = threadIdx.x;
  const int wav = tid>>6;
  const int lan = tid&63;

  const int cc  = lan>>4;
  const int b4  = beta>>2;
  const int q4  = beta&3;
  unsigned ph = 0;

  {
    const short8* g1 = (const short8*)(a.Wp1h + (size_t)beta*28672);
    short8* l1 = (short8*)Lw1;
    for (int i=tid; i<3584; i+=NT) l1[i] = g1[i];
    const short8* g2 = (const short8*)(a.Wp2h + (size_t)beta*40960);
    short8* l2 = (short8*)Lw2;
    for (int i=tid; i<5120; i+=NT) l2[i] = g2[i];
  }

  bool mv = false;
  if (tid<256) mv = (a.mflag[0] ? (a.mask32[b4*256+tid] != 0) : (a.mask8[b4*256+tid] != 0));
  __syncthreads();

  for (int tau=0; tau<=400; ++tau){
    const int p = tau&1;
    // ================= Phase A: LSTM1 (waves 0-3) ∥ LSTM2 (waves 4-7) =================
    if (tau<400 && wav<4){
      const int row = wav*16 + (lan&15);
      f32x4 A0={0.f,0.f,0.f,0.f};
      const unsigned short* wh = Lw1 + lan*8;
      {
        const unsigned short* xh = a.xbh + ((size_t)tau*64 + row)*256 + cc*8;
        #pragma unroll
        for(int kt=0;kt<8;kt++)
          A0=mfma16(*(const short8*)(xh+kt*32), *(const short8*)(wh+kt*512), A0);
      }
      {
        const unsigned short* xh = a.ctxh + row*512 + cc*8;
        #pragma unroll 8
        for(int kt=8;kt<24;kt++)
          A0=mfma16(ld8h(xh+(kt-8)*32), *(const short8*)(wh+kt*512), A0);
      }
      {
        const unsigned short* xh = a.h1h + (size_t)(p^1)*65536 + row*1024 + cc*8;
        #pragma unroll 8
        for(int kt=24;kt<56;kt++)
          A0=mfma16(ld8h(xh+(kt-24)*32), *(const short8*)(wh+kt*512), A0);
      }
      #pragma unroll
      for(int r=0;r<4;r++) gsc1[(wav*16 + cc*4 + r)*17 + (lan&15)] = A0[r];
    }
    if (tau>0 && wav>=4){
      const int wv2 = wav-4;
      const int row = wv2*16 + (lan&15);
      f32x4 A0={0.f,0.f,0.f,0.f};
      const unsigned short* wh = Lw2 + lan*8;
      {
        const unsigned short* xh = a.h1h + (size_t)(p^1)*65536 + row*1024 + cc*8;
        #pragma unroll 8
        for(int kt=0;kt<32;kt++)
          A0=mfma16(ld8h(xh+kt*32), *(const short8*)(wh+kt*512), A0);
      }
      {
        const unsigned short* xh = a.ctxh + row*512 + cc*8;
        #pragma unroll 8
        for(int kt=32;kt<48;kt++)
          A0=mfma16(ld8h(xh+(kt-32)*32), *(const short8*)(wh+kt*512), A0);
      }
      {
        const unsigned short* xh = a.h2h + (size_t)p*65536 + row*1024 + cc*8;
        #pragma unroll 8
        for(int kt=48;kt<80;kt++)
          A0=mfma16(ld8h(xh+(kt-48)*32), *(const short8*)(wh+kt*512), A0);
      }
      #pragma unroll
      for(int r=0;r<4;r++) gsc2[(wv2*16 + cc*4 + r)*17 + (lan&15)] = A0[r];
    }
    __syncthreads();
    if (tau<400 && tid<256){
      int m = tid>>2, j = tid&3, u = beta*4+j;
      float gi = gsc1[m*17+0+j]  + a.bsum1[0*1024+u];
      float gf = gsc1[m*17+4+j]  + a.bsum1[1*1024+u];
      float gg = gsc1[m*17+8+j]  + a.bsum1[2*1024+u];
      float go = gsc1[m*17+12+j] + a.bsum1[3*1024+u];
      float cp = a.c1[m*1024+u];
      float cn = sigm(gf)*cp + sigm(gi)*tanh_(gg);
      a.c1[m*1024+u] = cn;
      float hn = sigm(go)*tanh_(cn);
      stf(a.h1f + m*1024+u, hn);
      sth(a.h1h + (size_t)p*65536 + m*1024 + u, f2b(hn));
    }
    if (tau>0 && tid>=256){
      int t2 = tid-256;
      int m = t2>>2, j = t2&3, u = beta*4+j;
      float gi = gsc2[m*17+0+j]  + a.bsum2[0*1024+u];
      float gf = gsc2[m*17+4+j]  + a.bsum2[1*1024+u];
      float gg = gsc2[m*17+8+j]  + a.bsum2[2*1024+u];
      float go = gsc2[m*17+12+j] + a.bsum2[3*1024+u];
      float cp = a.c2[m*1024+u];
      float cn = sigm(gf)*cp + sigm(gi)*tanh_(gg);
      a.c2[m*1024+u] = cn;
      float hn = sigm(go)*tanh_(cn);
      stf(a.h2f + m*1024+u, hn);
      sth(a.h2h + (size_t)(p^1)*65536 + m*1024 + u, f2b(hn));
    }
    if (tau<400){
      if (tid<128){
        float2 v = ld2f(a.aw + b4*256 + tid*2);
        sA[tid*2]=v.x; sA[tid*2+1]=v.y;
        float2 w2 = ld2f(a.awc + b4*256 + tid*2);
        sA[256+tid*2]=w2.x; sA[257+tid*2]=w2.y;
      }
      for(int i=tid;i<1984;i+=NT) sA[512+i] = a.loc_conv[i];
    }
    __syncthreads();
    if (tau<400){
      const int t0 = q4*64;
      #pragma unroll
      for(int jj=0;jj<4;jj++){
        int o = tid*4+jj;
        int f = o>>6, tl = o&63, t = t0+tl;
        float s = 0.f;
        #pragma unroll
        for(int c=0;c<2;c++){
          const float* kw = &sA[512 + (f*2+c)*31];
          const float* wv = &sA[c*256];
          for(int k=0;k<31;k++){
            int tt = t + k - 15;
            if (tt>=0 && tt<256) s += wv[tt]*kw[k];
          }
        }
        stf(a.locT + (size_t)b4*8192 + f*256 + t, s);
      }
    }
    gbar2(a.arrive, a.root, a.release, grp, ph);
    // ================= Phase B: q/e path (tid<256) ∥ out-proj (tid 256-415) =================
    if (tau<400 && tid<256){
      for(int i=tid*2;i<1024;i+=512){
        float2 v = ld2f(a.h1f + b4*1024 + i);
        sA[i]=v.x; sA[i+1]=v.y;
      }
    }
    if (tau>0 && tid>=256){
      int t2 = tid-256;
      for(int i=t2*2;i<1024;i+=512){
        float2 v = ld2f(a.h2f + b4*1024 + i);
        sA[1024+i]=v.x; sA[1025+i]=v.y;
      }
      {
        float2 v = ld2f(a.ctxf + b4*512 + t2*2);
        sA[2048+t2*2]=v.x; sA[2049+t2*2]=v.y;
      }
    }
    __syncthreads();
    if (tau<400 && tid<256){
      int ml = tid>>3, sg = tid&7;
      const float* wq = a.Wq + (size_t)(q4*32+ml)*1024;
      float s=0.f;
      #pragma unroll 8
      for(int i=0;i<128;i++) s += sA[sg + i*8]*wq[sg + i*8];
      s += __shfl_xor(s,1); s += __shfl_xor(s,2); s += __shfl_xor(s,4);
      if (sg==0) sq[ml] = s;
    }
    if (tau>0 && tid>=256 && tid<416){
      int t2 = tid-256;
      int nl = t2>>3, sg = t2&7, nm = q4*20+nl;
      const float* wo = a.Wout + (size_t)nm*1536;
      float s=0.f;
      #pragma unroll 8
      for(int i=0;i<192;i++) s += sA[1024 + sg + i*8]*wo[sg + i*8];
      s += __shfl_xor(s,1); s += __shfl_xor(s,2); s += __shfl_xor(s,4);
      if (sg==0) a.outp[(size_t)b4*32000 + nm*400 + (tau-1)] = s + a.bout[nm];
    }
    __syncthreads();
    if (tau<400 && tid<256){
      for(int i=tid;i<1024;i+=256) sA[i] = a.Wloc[(q4*32 + (i>>5))*32 + (i&31)];
    }
    if (tid<32) sv[tid] = a.v_att[q4*32+tid];
    __syncthreads();
    if (tau<400 && tid<256){
      int t = tid;
      float lc[32];
      const float* lb = a.locT + (size_t)b4*8192 + t;
      #pragma unroll
      for(int f=0;f<32;f++) lc[f] = ldf(lb + f*256);
      const unsigned short* kb = a.keypT + ((size_t)b4*128 + q4*32)*256 + t;
      float acc=0.f;
      for(int mm=0;mm<32;mm++){
        float lf=0.f;
        #pragma unroll
        for(int f=0;f<32;f++) lf += lc[f]*sA[mm*32+f];
        acc += tanh_(sq[mm] + b2f(kb[mm*256]) + lf)*sv[mm];
      }
      stf(a.eP + b4*1024 + t*4 + q4, acc);
    }
    if (tau==400) break;
    gbar2(a.arrive, a.root, a.release, grp, ph);
    // ================= Phase C =================
    {
      float e=0.f, pe=0.f, mx=0.f;
      if (tid<256){
        const float* ep = a.eP + b4*1024 + tid*4;
        e = ldf(ep+0)+ldf(ep+1)+ldf(ep+2)+ldf(ep+3);
        if (!mv) e = -1e9f;
        mx = e;
        #pragma unroll
        for(int off=1;off<64;off<<=1) mx = fmaxf(mx, __shfl_xor(mx,off));
        if (lan==0) red[wav] = mx;
      }
      __syncthreads();
      if (tid<256){
        mx = fmaxf(fmaxf(red[0],red[1]), fmaxf(red[2],red[3]));
        pe = __expf(e-mx);
        float sm = pe;
        #pragma unroll
        for(int off=1;off<64;off<<=1) sm += __shfl_xor(sm,off);
        if (lan==0) red[4+wav] = sm;
      }
      __syncthreads();
      if (tid<256){
        float sm = red[4]+red[5]+red[6]+red[7];
        float awt = pe/sm;
        if (q4==0){
          stf(a.aw + b4*256+tid, awt);
          stf(a.awc + b4*256+tid, ldf(a.awc + b4*256+tid) + awt);
          a.wout[(size_t)b4*102400 + (size_t)tid*400 + tau] = awt;
        }
        sA[tid] = awt;
      }
      __syncthreads();
      {
        int fl = tid&127, th = tid>>7;
        const unsigned short* xp = a.xinh + ((size_t)(b4*256 + th*64))*512 + q4*128 + fl;
        float s=0.f;
        for(int i=0;i<64;i++) s += sA[th*64+i]*b2f(xp[(size_t)i*512]);
        sA[256+tid] = s;
      }
      __syncthreads();
      if (tid<128){
        float v = sA[256+tid] + sA[384+tid] + sA[512+tid] + sA[640+tid];
        int idx = b4*512 + q4*128 + tid;
        stf(a.ctxf + idx, v);
        sth(a.ctxh + idx, f2b(v));
      }
    }
    gbar2(a.arrive, a.root, a.release, grp, ph);
  }
}

extern "C" void kernel_launch(void* const* d_in, const int* in_sizes, int n_in,
                              void* d_out, int out_size, void* d_ws, size_t ws_size,
                              hipStream_t stream){
  (void)in_sizes; (void)n_in; (void)out_size; (void)ws_size;
  const float* xin   = (const float*)d_in[0];
  const float* target= (const float*)d_in[2];
  const float* Wpre1 = (const float*)d_in[3];
  const float* bpre1 = (const float*)d_in[4];
  const float* Wpre2 = (const float*)d_in[5];
  const float* bpre2 = (const float*)d_in[6];
  const float* Wq    = (const float*)d_in[7];
  const float* Wk    = (const float*)d_in[8];
  const float* loc_conv = (const float*)d_in[9];
  const float* Wloc  = (const float*)d_in[10];
  const float* v_att = (const float*)d_in[11];
  const float* Wih1  = (const float*)d_in[12];
  const float* Whh1  = (const float*)d_in[13];
  const float* bih1  = (const float*)d_in[14];
  const float* bhh1  = (const float*)d_in[15];
  const float* Wih2  = (const float*)d_in[16];
  const float* Whh2  = (const float*)d_in[17];
  const float* bih2  = (const float*)d_in[18];
  const float* bhh2  = (const float*)d_in[19];
  const float* Wout  = (const float*)d_in[20];
  const float* boutp = (const float*)d_in[21];

  char* w = (char*)d_ws;
  auto carve=[&](size_t bytes)->void*{ void* r=(void*)w; w += (bytes+255)&~(size_t)255; return r; };
  // state region (zeroed every launch) — must stay first & contiguous
  unsigned short* h1h = (unsigned short*)carve((size_t)2*64*1024*2);
  unsigned short* h2h = (unsigned short*)carve((size_t)2*64*1024*2);
  unsigned short* ctxh= (unsigned short*)carve((size_t)64*512*2);
  float* h1f = (float*)carve((size_t)64*1024*4);
  float* h2f = (float*)carve((size_t)64*1024*4);
  float* ctxf= (float*)carve((size_t)64*512*4);
  float* c1  = (float*)carve((size_t)64*1024*4);
  float* c2  = (float*)carve((size_t)64*1024*4);
  float* aw  = (float*)carve((size_t)64*256*4);
  float* awc = (float*)carve((size_t)64*256*4);
  unsigned* arrive  = (unsigned*)carve(1024);
  unsigned* rootc   = (unsigned*)carve(256);
  unsigned* release = (unsigned*)carve(1024);
  int* mflag = (int*)carve(256);
  size_t state_bytes = (size_t)(w - (char*)d_ws);
  float* eP   = (float*)carve((size_t)64*256*4*4);
  float* locT = (float*)carve((size_t)64*32*256*4);
  unsigned short* keypT = (unsigned short*)carve((size_t)64*128*256*2);
  unsigned short* xinh  = (unsigned short*)carve((size_t)64*256*512*2);
  unsigned short* xbh = (unsigned short*)carve((size_t)400*64*256*2);
  float* bsum1 = (float*)carve((size_t)4096*4);
  float* bsum2 = (float*)carve((size_t)4096*4);
  unsigned short* Wp1h = (unsigned short*)carve((size_t)256*56*512*2);
  unsigned short* Wp2h = (unsigned short*)carve((size_t)256*80*512*2);

  hipMemsetAsync(d_ws, 0, state_bytes, stream);
  maskdet_k<<<1, 256, 0, stream>>>((const unsigned*)d_in[1], mflag);
  xin2bf_k<<<32768, 256, 0, stream>>>(xin, xinh);
  prenet_k<<<400, 256, 0, stream>>>(target, Wpre1, bpre1, Wpre2, bpre2, xbh);
  keyproj_k<<<1024, 128, 0, stream>>>(xin, Wk, keypT);
  prep_k<<<16, 256, 0, stream>>>(bih1,bhh1,bih2,bhh2,bsum1,bsum2);
  perm_k<<<2048, 256, 0, stream>>>(Wih1,Whh1,Wih2,Whh2,Wp1h,Wp2h);

  SArgs a;
  a.xin=xin; a.loc_conv=loc_conv; a.Wloc=Wloc; a.v_att=v_att; a.bout=boutp;
  a.Wq=Wq; a.Wout=Wout;
  a.keypT=keypT; a.xinh=xinh; a.xbh=xbh;
  a.Wp1h=Wp1h; a.Wp2h=Wp2h;
  a.bsum1=bsum1; a.bsum2=bsum2;
  a.mask8=(const unsigned char*)d_in[1]; a.mask32=(const int*)d_in[1]; a.mflag=mflag;
  a.h1h=h1h; a.h1f=h1f;
  a.h2h=h2h; a.h2f=h2f;
  a.ctxh=ctxh; a.ctxf=ctxf;
  a.c1=c1; a.c2=c2;
  a.aw=aw; a.awc=awc; a.eP=eP; a.locT=locT;
  a.arrive=arrive; a.root=rootc; a.release=release;
  a.outp=(float*)d_out; a.wout=(float*)d_out + (size_t)64*80*400;

  hipFuncSetAttribute((const void*)scan_kernel, hipFuncAttributeMaxDynamicSharedMemorySize, DYNB);
  scan_kernel<<<dim3(NB), dim3(NT), DYNB, stream>>>(a);
}

// Round 21
// 46796.353 us; speedup vs baseline: 1.6528x; 1.0959x over previous
//
#include <hip/hip_runtime.h>

#define NB 256
#define NT 512
#define DYNB 158496
#define SCOPE __HIP_MEMORY_SCOPE_AGENT

typedef __attribute__((ext_vector_type(8))) short short8;
typedef __attribute__((ext_vector_type(4))) float f32x4;

__device__ __forceinline__ float b2f(unsigned short s){ return __uint_as_float(((unsigned)s)<<16); }
__device__ __forceinline__ unsigned short f2b(float f){
  unsigned u = __float_as_uint(f);
  return (unsigned short)((u + 0x7FFFu + ((u>>16)&1u))>>16);
}
__device__ __forceinline__ float sigm(float x){ return 1.0f/(1.0f+__expf(-x)); }
__device__ __forceinline__ float tanh_(float x){ float e=__expf(-2.0f*x); return (1.0f-e)/(1.0f+e); }
__device__ __forceinline__ f32x4 mfma16(short8 a, short8 b, f32x4 c){
  return __builtin_amdgcn_mfma_f32_16x16x32_bf16(a,b,c,0,0,0);
}

// device-coherent access (for same-step exchange buffers only)
__device__ __forceinline__ float2 ld2f(const float* p){
  union{ unsigned long long u; float2 f; } r;
  r.u = __hip_atomic_load((const unsigned long long*)p, __ATOMIC_RELAXED, SCOPE);
  return r.f;
}
__device__ __forceinline__ float ldf(const float* p){
  return __hip_atomic_load((float*)p, __ATOMIC_RELAXED, SCOPE);
}
__device__ __forceinline__ void stf(float* p, float v){
  __hip_atomic_store(p, v, __ATOMIC_RELAXED, SCOPE);
}
__device__ __forceinline__ void sth(unsigned short* p, unsigned short v){
  __hip_atomic_store(p, v, __ATOMIC_RELAXED, SCOPE);
}

// hierarchical grid barrier (R20-proven)
__device__ __forceinline__ void gbar2(unsigned* arrive, unsigned* root, unsigned* release,
                                      int grp, unsigned& ph){
  __syncthreads();
  if (threadIdx.x==0){
    ph += 1;
    asm volatile("s_waitcnt vmcnt(0)" ::: "memory");
    unsigned old = __hip_atomic_fetch_add(&arrive[grp*32], 1u, __ATOMIC_RELAXED, SCOPE);
    if (old == ph*32u - 1u){
      __hip_atomic_fetch_add(root, 1u, __ATOMIC_RELAXED, SCOPE);
      while (__hip_atomic_load(root, __ATOMIC_RELAXED, SCOPE) < ph*8u){
        __builtin_amdgcn_s_sleep(1);
      }
      __hip_atomic_store(&release[grp*32], ph, __ATOMIC_RELAXED, SCOPE);
    } else {
      while (__hip_atomic_load(&release[grp*32], __ATOMIC_RELAXED, SCOPE) < ph){
        __builtin_amdgcn_s_sleep(1);
      }
    }
  }
  __syncthreads();
}

// ---------------- precompute kernels ----------------

__global__ void maskdet_k(const unsigned* __restrict__ m32, int* __restrict__ flag){
  __shared__ int ok;
  if (threadIdx.x==0) ok = 1;
  __syncthreads();
  for (int i=threadIdx.x; i<4096; i+=256){
    if (m32[i] > 1u) ok = 0;
  }
  __syncthreads();
  if (threadIdx.x==0) *flag = ok;
}

__global__ void xin2bf_k(const float* __restrict__ xin, unsigned short* __restrict__ xinh){
  size_t i = (size_t)blockIdx.x*256 + threadIdx.x;
  if (i < (size_t)64*256*512) xinh[i] = f2b(xin[i]);
}

__global__ void prenet_k(const float* __restrict__ target, const float* __restrict__ W1, const float* __restrict__ b1,
                         const float* __restrict__ W2, const float* __restrict__ b2,
                         unsigned short* __restrict__ xbh){
  int t = blockIdx.x;
  int tid = threadIdx.x;
  __shared__ float stgt[64][80];
  __shared__ float smid[64][256];
  for(int i=tid;i<64*80;i+=256){
    int b=i/80, c=i%80;
    stgt[b][c] = (t==0)?0.f : target[((size_t)b*80+c)*400 + (t-1)];
  }
  __syncthreads();
  {
    float w1r[80];
    #pragma unroll
    for(int c=0;c<80;c++) w1r[c] = W1[tid*80+c];
    float bb1 = b1[tid];
    for(int b0=0;b0<64;b0+=16){
      float acc[16];
      #pragma unroll
      for(int i=0;i<16;i++) acc[i]=0.f;
      for(int c=0;c<80;c++){
        float wv=w1r[c];
        #pragma unroll
        for(int i=0;i<16;i++) acc[i] += wv*stgt[b0+i][c];
      }
      #pragma unroll
      for(int i=0;i<16;i++) smid[b0+i][tid] = fmaxf(acc[i]+bb1, 0.f);
    }
  }
  __syncthreads();
  {
    float bb2 = b2[tid];
    for(int b0=0;b0<64;b0+=16){
      float acc[16];
      #pragma unroll
      for(int i=0;i<16;i++) acc[i]=0.f;
      for(int c=0;c<256;c++){
        float wv=W2[tid*256+c];
        #pragma unroll
        for(int i=0;i<16;i++) acc[i] += wv*smid[b0+i][c];
      }
      #pragma unroll
      for(int i=0;i<16;i++){
        float v = fmaxf(acc[i]+bb2,0.f);
        xbh[((size_t)t*64 + b0+i)*256 + tid] = f2b(v);
      }
    }
  }
}

__global__ void keyproj_k(const float* __restrict__ xin, const float* __restrict__ Wk, unsigned short* __restrict__ keypT){
  int b = blockIdx.x>>4; int t0=(blockIdx.x&15)*16; int m=threadIdx.x; // 128 threads
  __shared__ float sx[16][512];
  for(int i=m;i<16*512;i+=128){ int tt=i>>9, f=i&511; sx[tt][f]=xin[((size_t)b*256+t0+tt)*512+f]; }
  __syncthreads();
  float s[16];
  #pragma unroll
  for(int i=0;i<16;i++) s[i]=0.f;
  for(int f=0;f<512;f++){
    float wv = Wk[m*512+f];
    #pragma unroll
    for(int i=0;i<16;i++) s[i]+=sx[i][f]*wv;
  }
  #pragma unroll
  for(int i=0;i<16;i++) keypT[((size_t)b*128+m)*256 + t0+i] = f2b(s[i]);
}

__global__ void prep_k(const float* bih1,const float* bhh1,const float* bih2,const float* bhh2,
                       float* bsum1,float* bsum2){
  int i0 = blockIdx.x*blockDim.x + threadIdx.x;
  int n = gridDim.x*blockDim.x;
  for(int k=i0;k<4096;k+=n){ bsum1[k]=bih1[k]+bhh1[k]; bsum2[k]=bih2[k]+bhh2[k]; }
}

__global__ void perm_k(const float* __restrict__ Wih1, const float* __restrict__ Whh1,
                       const float* __restrict__ Wih2, const float* __restrict__ Whh2,
                       unsigned short* __restrict__ Wp1h, unsigned short* __restrict__ Wp2h){
  size_t i0 = (size_t)blockIdx.x*blockDim.x + threadIdx.x;
  size_t n  = (size_t)gridDim.x*blockDim.x;
  const size_t N1 = (size_t)256*56*512;
  for(size_t idx=i0; idx<N1; idx+=n){
    int beta = (int)(idx/28672);
    int r = (int)(idx%28672);
    int kt = r/512;
    int l  = (r>>3)&63;
    int i8 = r&7;
    int c = l&15, cci = l>>4;
    int k = kt*32 + cci*8 + i8;
    int rowp = (c>>2)*1024 + beta*4 + (c&3);
    float v = (k<768)? Wih1[(size_t)rowp*768 + k] : Whh1[(size_t)rowp*1024 + (k-768)];
    Wp1h[idx] = f2b(v);
  }
  const size_t N2 = (size_t)256*80*512;
  for(size_t idx=i0; idx<N2; idx+=n){
    int beta = (int)(idx/40960);
    int r = (int)(idx%40960);
    int kt = r/512;
    int l  = (r>>3)&63;
    int i8 = r&7;
    int c = l&15, cci = l>>4;
    int k = kt*32 + cci*8 + i8;
    int rowp = (c>>2)*1024 + beta*4 + (c&3);
    float v = (k<1536)? Wih2[(size_t)rowp*1536 + k] : Whh2[(size_t)rowp*1024 + (k-1536)];
    Wp2h[idx] = f2b(v);
  }
}

// ---------------- the scan (rotating state buffers -> cached broadcast) ----------------

struct SArgs {
  const float* loc_conv; const float* v_att; const float* bout;
  const float* Wq; const float* Wout; const float* Wloc;
  const unsigned short* keypT; const unsigned short* xinh;
  const unsigned short* xbh;
  const unsigned short* Wp1h; const unsigned short* Wp2h;
  const float* bsum1; const float* bsum2;
  const unsigned char* mask8; const int* mask32; const int* mflag;
  unsigned short* h1rot; unsigned short* h2rot; unsigned short* ctxrot;
  const unsigned short* zbuf;
  float* c1; float* c2;
  float* aw; float* awc; float* eP; float* locT;
  unsigned* arrive; unsigned* root; unsigned* release;
  float* outp; float* wout;
};

__global__ void __launch_bounds__(NT) scan_kernel(SArgs a){
  extern __shared__ char dynsm[];
  unsigned short* Lw1 = (unsigned short*)dynsm;             // 28672
  unsigned short* Lw2 = (unsigned short*)(dynsm + 57344);   // 40960
  float* gsc1 = (float*)(dynsm + 139264);                   // [64][17]
  float* gsc2 = (float*)(dynsm + 143616);                   // [64][17]
  float* sA   = (float*)(dynsm + 147968);                   // [2560]
  float* sq   = (float*)(dynsm + 158208);                   // [32]
  float* sv   = (float*)(dynsm + 158336);                   // [32]
  float* red  = (float*)(dynsm + 158464);                   // [8]

  const int beta = ((blockIdx.x & 7) << 5) | (blockIdx.x >> 3);  // XCD-chunked
  const int grp  = blockIdx.x & 7;
  const int tid = threadIdx.x;
  const int wav = tid>>6;
  const int lan = tid&63;

  const int cc  = lan>>4;
  const int b4  = beta>>2;
  const int q4  = beta&3;
  unsigned ph = 0;

  {
    const short8* g1 = (const short8*)(a.Wp1h + (size_t)beta*28672);
    short8* l1 = (short8*)Lw1;
    for (int i=tid; i<3584; i+=NT) l1[i] = g1[i];
    const short8* g2 = (const short8*)(a.Wp2h + (size_t)beta*40960);
    short8* l2 = (short8*)Lw2;
    for (int i=tid; i<5120; i+=NT) l2[i] = g2[i];
  }

  bool mv = false;
  if (tid<256) mv = (a.mflag[0] ? (a.mask32[b4*256+tid] != 0) : (a.mask8[b4*256+tid] != 0));
  __syncthreads();

  for (int tau=0; tau<=400; ++tau){
    // rotating-slot pointers: fresh addresses each step => normal cached loads
    // are guaranteed-fresh (never-cached lines), and 32 blocks/XCD share L2 hits.
    const unsigned short* h1p = (tau==0)? a.zbuf : a.h1rot + (size_t)(tau-1)*65536;
    const unsigned short* h2p = (tau<=1)? a.zbuf : a.h2rot + (size_t)(tau-2)*65536;
    const unsigned short* cxp = (tau==0)? a.zbuf : a.ctxrot + (size_t)(tau-1)*32768;
    unsigned short* h1w = a.h1rot + (size_t)tau*65536;
    unsigned short* h2w = a.h2rot + (size_t)(tau>0 ? tau-1 : 0)*65536;
    unsigned short* cxw = a.ctxrot + (size_t)tau*32768;

    // ================= Phase A: LSTM1 (waves 0-3) ∥ LSTM2 (waves 4-7) =================
    if (tau<400 && wav<4){
      const int row = wav*16 + (lan&15);
      f32x4 A0={0.f,0.f,0.f,0.f};
      const unsigned short* wh = Lw1 + lan*8;
      {
        const unsigned short* xh = a.xbh + ((size_t)tau*64 + row)*256 + cc*8;
        #pragma unroll
        for(int kt=0;kt<8;kt++)
          A0=mfma16(*(const short8*)(xh+kt*32), *(const short8*)(wh+kt*512), A0);
      }
      {
        const unsigned short* xh = cxp + row*512 + cc*8;
        #pragma unroll 8
        for(int kt=8;kt<24;kt++)
          A0=mfma16(*(const short8*)(xh+(kt-8)*32), *(const short8*)(wh+kt*512), A0);
      }
      {
        const unsigned short* xh = h1p + row*1024 + cc*8;
        #pragma unroll 8
        for(int kt=24;kt<56;kt++)
          A0=mfma16(*(const short8*)(xh+(kt-24)*32), *(const short8*)(wh+kt*512), A0);
      }
      #pragma unroll
      for(int r=0;r<4;r++) gsc1[(wav*16 + cc*4 + r)*17 + (lan&15)] = A0[r];
    }
    if (tau>0 && wav>=4){
      const int wv2 = wav-4;
      const int row = wv2*16 + (lan&15);
      f32x4 A0={0.f,0.f,0.f,0.f};
      const unsigned short* wh = Lw2 + lan*8;
      {
        const unsigned short* xh = h1p + row*1024 + cc*8;
        #pragma unroll 8
        for(int kt=0;kt<32;kt++)
          A0=mfma16(*(const short8*)(xh+kt*32), *(const short8*)(wh+kt*512), A0);
      }
      {
        const unsigned short* xh = cxp + row*512 + cc*8;
        #pragma unroll 8
        for(int kt=32;kt<48;kt++)
          A0=mfma16(*(const short8*)(xh+(kt-32)*32), *(const short8*)(wh+kt*512), A0);
      }
      {
        const unsigned short* xh = h2p + row*1024 + cc*8;
        #pragma unroll 8
        for(int kt=48;kt<80;kt++)
          A0=mfma16(*(const short8*)(xh+(kt-48)*32), *(const short8*)(wh+kt*512), A0);
      }
      #pragma unroll
      for(int r=0;r<4;r++) gsc2[(wv2*16 + cc*4 + r)*17 + (lan&15)] = A0[r];
    }
    __syncthreads();
    if (tau<400 && tid<256){
      int m = tid>>2, j = tid&3, u = beta*4+j;
      float gi = gsc1[m*17+0+j]  + a.bsum1[0*1024+u];
      float gf = gsc1[m*17+4+j]  + a.bsum1[1*1024+u];
      float gg = gsc1[m*17+8+j]  + a.bsum1[2*1024+u];
      float go = gsc1[m*17+12+j] + a.bsum1[3*1024+u];
      float cp = a.c1[m*1024+u];
      float cn = sigm(gf)*cp + sigm(gi)*tanh_(gg);
      a.c1[m*1024+u] = cn;
      float hn = sigm(go)*tanh_(cn);
      sth(h1w + m*1024 + u, f2b(hn));
    }
    if (tau>0 && tid>=256){
      int t2 = tid-256;
      int m = t2>>2, j = t2&3, u = beta*4+j;
      float gi = gsc2[m*17+0+j]  + a.bsum2[0*1024+u];
      float gf = gsc2[m*17+4+j]  + a.bsum2[1*1024+u];
      float gg = gsc2[m*17+8+j]  + a.bsum2[2*1024+u];
      float go = gsc2[m*17+12+j] + a.bsum2[3*1024+u];
      float cp = a.c2[m*1024+u];
      float cn = sigm(gf)*cp + sigm(gi)*tanh_(gg);
      a.c2[m*1024+u] = cn;
      float hn = sigm(go)*tanh_(cn);
      sth(h2w + m*1024 + u, f2b(hn));
    }
    if (tau<400){
      if (tid<128){
        float2 v = ld2f(a.aw + b4*256 + tid*2);
        sA[tid*2]=v.x; sA[tid*2+1]=v.y;
        float2 w2 = ld2f(a.awc + b4*256 + tid*2);
        sA[256+tid*2]=w2.x; sA[257+tid*2]=w2.y;
      }
      for(int i=tid;i<1984;i+=NT) sA[512+i] = a.loc_conv[i];
    }
    __syncthreads();
    if (tau<400){
      const int t0 = q4*64;
      #pragma unroll
      for(int jj=0;jj<4;jj++){
        int o = tid*4+jj;
        int f = o>>6, tl = o&63, t = t0+tl;
        float s = 0.f;
        #pragma unroll
        for(int c=0;c<2;c++){
          const float* kw = &sA[512 + (f*2+c)*31];
          const float* wv = &sA[c*256];
          for(int k=0;k<31;k++){
            int tt = t + k - 15;
            if (tt>=0 && tt<256) s += wv[tt]*kw[k];
          }
        }
        stf(a.locT + (size_t)b4*8192 + f*256 + t, s);
      }
    }
    gbar2(a.arrive, a.root, a.release, grp, ph);
    // ================= Phase B: q/e path (tid<256) ∥ out-proj (tid 256-415) =================
    if (tau<400 && tid<256){
      const unsigned short* h1c = a.h1rot + (size_t)tau*65536 + b4*1024;
      for(int i=tid;i<1024;i+=256) sA[i] = b2f(h1c[i]);
    }
    if (tau>0 && tid>=256){
      int t2 = tid-256;
      const unsigned short* h2c = a.h2rot + (size_t)(tau-1)*65536 + b4*1024;
      const unsigned short* cxc = a.ctxrot + (size_t)(tau-1)*32768 + b4*512;
      for(int i=t2;i<1024;i+=256) sA[1024+i] = b2f(h2c[i]);
      for(int i=t2;i<512;i+=256)  sA[2048+i] = b2f(cxc[i]);
    }
    __syncthreads();
    if (tau<400 && tid<256){
      int ml = tid>>3, sg = tid&7;
      const float* wq = a.Wq + (size_t)(q4*32+ml)*1024;
      float s=0.f;
      #pragma unroll 8
      for(int i=0;i<128;i++) s += sA[sg + i*8]*wq[sg + i*8];
      s += __shfl_xor(s,1); s += __shfl_xor(s,2); s += __shfl_xor(s,4);
      if (sg==0) sq[ml] = s;
    }
    if (tau>0 && tid>=256 && tid<416){
      int t2 = tid-256;
      int nl = t2>>3, sg = t2&7, nm = q4*20+nl;
      const float* wo = a.Wout + (size_t)nm*1536;
      float s=0.f;
      #pragma unroll 8
      for(int i=0;i<192;i++) s += sA[1024 + sg + i*8]*wo[sg + i*8];
      s += __shfl_xor(s,1); s += __shfl_xor(s,2); s += __shfl_xor(s,4);
      if (sg==0) a.outp[(size_t)b4*32000 + nm*400 + (tau-1)] = s + a.bout[nm];
    }
    __syncthreads();
    if (tau<400 && tid<256){
      for(int i=tid;i<1024;i+=256) sA[i] = a.Wloc[(q4*32 + (i>>5))*32 + (i&31)];
    }
    if (tid<32) sv[tid] = a.v_att[q4*32+tid];
    __syncthreads();
    if (tau<400 && tid<256){
      int t = tid;
      float lc[32];
      const float* lb = a.locT + (size_t)b4*8192 + t;
      #pragma unroll
      for(int f=0;f<32;f++) lc[f] = ldf(lb + f*256);
      const unsigned short* kb = a.keypT + ((size_t)b4*128 + q4*32)*256 + t;
      float acc=0.f;
      for(int mm=0;mm<32;mm++){
        float lf=0.f;
        #pragma unroll
        for(int f=0;f<32;f++) lf += lc[f]*sA[mm*32+f];
        acc += tanh_(sq[mm] + b2f(kb[mm*256]) + lf)*sv[mm];
      }
      stf(a.eP + b4*1024 + t*4 + q4, acc);
    }
    if (tau==400) break;
    gbar2(a.arrive, a.root, a.release, grp, ph);
    // ================= Phase C =================
    {
      float e=0.f, pe=0.f, mx=0.f;
      if (tid<256){
        const float* ep = a.eP + b4*1024 + tid*4;
        e = ldf(ep+0)+ldf(ep+1)+ldf(ep+2)+ldf(ep+3);
        if (!mv) e = -1e9f;
        mx = e;
        #pragma unroll
        for(int off=1;off<64;off<<=1) mx = fmaxf(mx, __shfl_xor(mx,off));
        if (lan==0) red[wav] = mx;
      }
      __syncthreads();
      if (tid<256){
        mx = fmaxf(fmaxf(red[0],red[1]), fmaxf(red[2],red[3]));
        pe = __expf(e-mx);
        float sm = pe;
        #pragma unroll
        for(int off=1;off<64;off<<=1) sm += __shfl_xor(sm,off);
        if (lan==0) red[4+wav] = sm;
      }
      __syncthreads();
      if (tid<256){
        float sm = red[4]+red[5]+red[6]+red[7];
        float awt = pe/sm;
        if (q4==0){
          stf(a.aw + b4*256+tid, awt);
          stf(a.awc + b4*256+tid, ldf(a.awc + b4*256+tid) + awt);
          a.wout[(size_t)b4*102400 + (size_t)tid*400 + tau] = awt;
        }
        sA[tid] = awt;
      }
      __syncthreads();
      {
        int fl = tid&127, th = tid>>7;
        const unsigned short* xp = a.xinh + ((size_t)(b4*256 + th*64))*512 + q4*128 + fl;
        float s=0.f;
        for(int i=0;i<64;i++) s += sA[th*64+i]*b2f(xp[(size_t)i*512]);
        sA[256+tid] = s;
      }
      __syncthreads();
      if (tid<128){
        float v = sA[256+tid] + sA[384+tid] + sA[512+tid] + sA[640+tid];
        sth(cxw + b4*512 + q4*128 + tid, f2b(v));
      }
    }
    gbar2(a.arrive, a.root, a.release, grp, ph);
  }
}

extern "C" void kernel_launch(void* const* d_in, const int* in_sizes, int n_in,
                              void* d_out, int out_size, void* d_ws, size_t ws_size,
                              hipStream_t stream){
  (void)in_sizes; (void)n_in; (void)out_size; (void)ws_size;
  const float* xin   = (const float*)d_in[0];
  const float* target= (const float*)d_in[2];
  const float* Wpre1 = (const float*)d_in[3];
  const float* bpre1 = (const float*)d_in[4];
  const float* Wpre2 = (const float*)d_in[5];
  const float* bpre2 = (const float*)d_in[6];
  const float* Wq    = (const float*)d_in[7];
  const float* Wk    = (const float*)d_in[8];
  const float* loc_conv = (const float*)d_in[9];
  const float* Wloc  = (const float*)d_in[10];
  const float* v_att = (const float*)d_in[11];
  const float* Wih1  = (const float*)d_in[12];
  const float* Whh1  = (const float*)d_in[13];
  const float* bih1  = (const float*)d_in[14];
  const float* bhh1  = (const float*)d_in[15];
  const float* Wih2  = (const float*)d_in[16];
  const float* Whh2  = (const float*)d_in[17];
  const float* bih2  = (const float*)d_in[18];
  const float* bhh2  = (const float*)d_in[19];
  const float* Wout  = (const float*)d_in[20];
  const float* boutp = (const float*)d_in[21];

  char* w = (char*)d_ws;
  auto carve=[&](size_t bytes)->void*{ void* r=(void*)w; w += (bytes+255)&~(size_t)255; return r; };
  // state region (zeroed every launch) — must stay first & contiguous
  unsigned short* zbuf = (unsigned short*)carve((size_t)64*1024*2);  // zero slot (h1-shaped, covers ctx too)
  float* c1  = (float*)carve((size_t)64*1024*4);
  float* c2  = (float*)carve((size_t)64*1024*4);
  float* aw  = (float*)carve((size_t)64*256*4);
  float* awc = (float*)carve((size_t)64*256*4);
  unsigned* arrive  = (unsigned*)carve(1024);
  unsigned* rootc   = (unsigned*)carve(256);
  unsigned* release = (unsigned*)carve(1024);
  int* mflag = (int*)carve(256);
  size_t state_bytes = (size_t)(w - (char*)d_ws);
  float* eP   = (float*)carve((size_t)64*256*4*4);
  float* locT = (float*)carve((size_t)64*32*256*4);
  unsigned short* keypT = (unsigned short*)carve((size_t)64*128*256*2);
  unsigned short* xinh  = (unsigned short*)carve((size_t)64*256*512*2);
  unsigned short* xbh = (unsigned short*)carve((size_t)400*64*256*2);
  float* bsum1 = (float*)carve((size_t)4096*4);
  float* bsum2 = (float*)carve((size_t)4096*4);
  unsigned short* Wp1h = (unsigned short*)carve((size_t)256*56*512*2);
  unsigned short* Wp2h = (unsigned short*)carve((size_t)256*80*512*2);
  unsigned short* h1rot = (unsigned short*)carve((size_t)400*65536*2);
  unsigned short* h2rot = (unsigned short*)carve((size_t)400*65536*2);
  unsigned short* ctxrot= (unsigned short*)carve((size_t)400*32768*2);

  hipMemsetAsync(d_ws, 0, state_bytes, stream);
  maskdet_k<<<1, 256, 0, stream>>>((const unsigned*)d_in[1], mflag);
  xin2bf_k<<<32768, 256, 0, stream>>>(xin, xinh);
  prenet_k<<<400, 256, 0, stream>>>(target, Wpre1, bpre1, Wpre2, bpre2, xbh);
  keyproj_k<<<1024, 128, 0, stream>>>(xin, Wk, keypT);
  prep_k<<<16, 256, 0, stream>>>(bih1,bhh1,bih2,bhh2,bsum1,bsum2);
  perm_k<<<2048, 256, 0, stream>>>(Wih1,Whh1,Wih2,Whh2,Wp1h,Wp2h);

  SArgs a;
  a.loc_conv=loc_conv; a.v_att=v_att; a.bout=boutp;
  a.Wq=Wq; a.Wout=Wout; a.Wloc=Wloc;
  a.keypT=keypT; a.xinh=xinh; a.xbh=xbh;
  a.Wp1h=Wp1h; a.Wp2h=Wp2h;
  a.bsum1=bsum1; a.bsum2=bsum2;
  a.mask8=(const unsigned char*)d_in[1]; a.mask32=(const int*)d_in[1]; a.mflag=mflag;
  a.h1rot=h1rot; a.h2rot=h2rot; a.ctxrot=ctxrot; a.zbuf=zbuf;
  a.c1=c1; a.c2=c2;
  a.aw=aw; a.awc=awc; a.eP=eP; a.locT=locT;
  a.arrive=arrive; a.root=rootc; a.release=release;
  a.outp=(float*)d_out; a.wout=(float*)d_out + (size_t)64*80*400;

  hipFuncSetAttribute((const void*)scan_kernel, hipFuncAttributeMaxDynamicSharedMemorySize, DYNB);
  scan_kernel<<<dim3(NB), dim3(NT), DYNB, stream>>>(a);
}

// Round 22
// 45517.206 us; speedup vs baseline: 1.6993x; 1.0281x over previous
//
#include <hip/hip_runtime.h>

#define NB 256
#define NT 512
#define DYNB 158496
#define SCOPE __HIP_MEMORY_SCOPE_AGENT

typedef __attribute__((ext_vector_type(8))) short short8;
typedef __attribute__((ext_vector_type(4))) float f32x4;

__device__ __forceinline__ float b2f(unsigned short s){ return __uint_as_float(((unsigned)s)<<16); }
__device__ __forceinline__ unsigned short f2b(float f){
  unsigned u = __float_as_uint(f);
  return (unsigned short)((u + 0x7FFFu + ((u>>16)&1u))>>16);
}
__device__ __forceinline__ float sigm(float x){ return 1.0f/(1.0f+__expf(-x)); }
__device__ __forceinline__ float tanh_(float x){ float e=__expf(-2.0f*x); return (1.0f-e)/(1.0f+e); }
__device__ __forceinline__ f32x4 mfma16(short8 a, short8 b, f32x4 c){
  return __builtin_amdgcn_mfma_f32_16x16x32_bf16(a,b,c,0,0,0);
}

// device-coherent access (same-step exchange buffers only)
__device__ __forceinline__ float2 ld2f(const float* p){
  union{ unsigned long long u; float2 f; } r;
  r.u = __hip_atomic_load((const unsigned long long*)p, __ATOMIC_RELAXED, SCOPE);
  return r.f;
}
__device__ __forceinline__ float ldf(const float* p){
  return __hip_atomic_load((float*)p, __ATOMIC_RELAXED, SCOPE);
}
__device__ __forceinline__ unsigned short ldh(const unsigned short* p){
  return __hip_atomic_load((unsigned short*)p, __ATOMIC_RELAXED, SCOPE);
}
__device__ __forceinline__ void stf(float* p, float v){
  __hip_atomic_store(p, v, __ATOMIC_RELAXED, SCOPE);
}
__device__ __forceinline__ void sth(unsigned short* p, unsigned short v){
  __hip_atomic_store(p, v, __ATOMIC_RELAXED, SCOPE);
}

// hierarchical grid barrier (R20-proven)
__device__ __forceinline__ void gbar2(unsigned* arrive, unsigned* root, unsigned* release,
                                      int grp, unsigned& ph){
  __syncthreads();
  if (threadIdx.x==0){
    ph += 1;
    asm volatile("s_waitcnt vmcnt(0)" ::: "memory");
    unsigned old = __hip_atomic_fetch_add(&arrive[grp*32], 1u, __ATOMIC_RELAXED, SCOPE);
    if (old == ph*32u - 1u){
      __hip_atomic_fetch_add(root, 1u, __ATOMIC_RELAXED, SCOPE);
      while (__hip_atomic_load(root, __ATOMIC_RELAXED, SCOPE) < ph*8u){
        __builtin_amdgcn_s_sleep(1);
      }
      __hip_atomic_store(&release[grp*32], ph, __ATOMIC_RELAXED, SCOPE);
    } else {
      while (__hip_atomic_load(&release[grp*32], __ATOMIC_RELAXED, SCOPE) < ph){
        __builtin_amdgcn_s_sleep(1);
      }
    }
  }
  __syncthreads();
}

// ---------------- precompute kernels ----------------

__global__ void maskdet_k(const unsigned* __restrict__ m32, int* __restrict__ flag){
  __shared__ int ok;
  if (threadIdx.x==0) ok = 1;
  __syncthreads();
  for (int i=threadIdx.x; i<4096; i+=256){
    if (m32[i] > 1u) ok = 0;
  }
  __syncthreads();
  if (threadIdx.x==0) *flag = ok;
}

__global__ void xin2bf_k(const float* __restrict__ xin, unsigned short* __restrict__ xinh){
  size_t i = (size_t)blockIdx.x*256 + threadIdx.x;
  if (i < (size_t)64*256*512) xinh[i] = f2b(xin[i]);
}

__global__ void prenet_k(const float* __restrict__ target, const float* __restrict__ W1, const float* __restrict__ b1,
                         const float* __restrict__ W2, const float* __restrict__ b2,
                         unsigned short* __restrict__ xbh){
  int t = blockIdx.x;
  int tid = threadIdx.x;
  __shared__ float stgt[64][80];
  __shared__ float smid[64][256];
  for(int i=tid;i<64*80;i+=256){
    int b=i/80, c=i%80;
    stgt[b][c] = (t==0)?0.f : target[((size_t)b*80+c)*400 + (t-1)];
  }
  __syncthreads();
  {
    float w1r[80];
    #pragma unroll
    for(int c=0;c<80;c++) w1r[c] = W1[tid*80+c];
    float bb1 = b1[tid];
    for(int b0=0;b0<64;b0+=16){
      float acc[16];
      #pragma unroll
      for(int i=0;i<16;i++) acc[i]=0.f;
      for(int c=0;c<80;c++){
        float wv=w1r[c];
        #pragma unroll
        for(int i=0;i<16;i++) acc[i] += wv*stgt[b0+i][c];
      }
      #pragma unroll
      for(int i=0;i<16;i++) smid[b0+i][tid] = fmaxf(acc[i]+bb1, 0.f);
    }
  }
  __syncthreads();
  {
    float bb2 = b2[tid];
    for(int b0=0;b0<64;b0+=16){
      float acc[16];
      #pragma unroll
      for(int i=0;i<16;i++) acc[i]=0.f;
      for(int c=0;c<256;c++){
        float wv=W2[tid*256+c];
        #pragma unroll
        for(int i=0;i<16;i++) acc[i] += wv*smid[b0+i][c];
      }
      #pragma unroll
      for(int i=0;i<16;i++){
        float v = fmaxf(acc[i]+bb2,0.f);
        xbh[((size_t)t*64 + b0+i)*256 + tid] = f2b(v);
      }
    }
  }
}

__global__ void keyproj_k(const float* __restrict__ xin, const float* __restrict__ Wk, unsigned short* __restrict__ keypT){
  int b = blockIdx.x>>4; int t0=(blockIdx.x&15)*16; int m=threadIdx.x; // 128 threads
  __shared__ float sx[16][512];
  for(int i=m;i<16*512;i+=128){ int tt=i>>9, f=i&511; sx[tt][f]=xin[((size_t)b*256+t0+tt)*512+f]; }
  __syncthreads();
  float s[16];
  #pragma unroll
  for(int i=0;i<16;i++) s[i]=0.f;
  for(int f=0;f<512;f++){
    float wv = Wk[m*512+f];
    #pragma unroll
    for(int i=0;i<16;i++) s[i]+=sx[i][f]*wv;
  }
  #pragma unroll
  for(int i=0;i<16;i++) keypT[((size_t)b*128+m)*256 + t0+i] = f2b(s[i]);
}

__global__ void prep_k(const float* bih1,const float* bhh1,const float* bih2,const float* bhh2,
                       const float* Wq, const float* Wout,
                       float* bsum1,float* bsum2,
                       unsigned short* WqH, unsigned short* WoutH){
  int i0 = blockIdx.x*blockDim.x + threadIdx.x;
  int n = gridDim.x*blockDim.x;
  for(int k=i0;k<4096;k+=n){ bsum1[k]=bih1[k]+bhh1[k]; bsum2[k]=bih2[k]+bhh2[k]; }
  for(int k=i0;k<128*1024;k+=n) WqH[k]=f2b(Wq[k]);
  for(int k=i0;k<80*1536;k+=n) WoutH[k]=f2b(Wout[k]);
}

__global__ void perm_k(const float* __restrict__ Wih1, const float* __restrict__ Whh1,
                       const float* __restrict__ Wih2, const float* __restrict__ Whh2,
                       unsigned short* __restrict__ Wp1h, unsigned short* __restrict__ Wp2h){
  size_t i0 = (size_t)blockIdx.x*blockDim.x + threadIdx.x;
  size_t n  = (size_t)gridDim.x*blockDim.x;
  const size_t N1 = (size_t)256*56*512;
  for(size_t idx=i0; idx<N1; idx+=n){
    int beta = (int)(idx/28672);
    int r = (int)(idx%28672);
    int kt = r/512;
    int l  = (r>>3)&63;
    int i8 = r&7;
    int c = l&15, cci = l>>4;
    int k = kt*32 + cci*8 + i8;
    int rowp = (c>>2)*1024 + beta*4 + (c&3);
    float v = (k<768)? Wih1[(size_t)rowp*768 + k] : Whh1[(size_t)rowp*1024 + (k-768)];
    Wp1h[idx] = f2b(v);
  }
  const size_t N2 = (size_t)256*80*512;
  for(size_t idx=i0; idx<N2; idx+=n){
    int beta = (int)(idx/40960);
    int r = (int)(idx%40960);
    int kt = r/512;
    int l  = (r>>3)&63;
    int i8 = r&7;
    int c = l&15, cci = l>>4;
    int k = kt*32 + cci*8 + i8;
    int rowp = (c>>2)*1024 + beta*4 + (c&3);
    float v = (k<1536)? Wih2[(size_t)rowp*1536 + k] : Whh2[(size_t)rowp*1024 + (k-1536)];
    Wp2h[idx] = f2b(v);
  }
}

// ---------------- the scan ----------------

struct SArgs {
  const float* loc_conv; const float* v_att; const float* bout;
  const unsigned short* WqH; const unsigned short* WoutH; const float* Wloc;
  const unsigned short* keypT; const unsigned short* xinh;
  const unsigned short* xbh;
  const unsigned short* Wp1h; const unsigned short* Wp2h;
  const float* bsum1; const float* bsum2;
  const unsigned char* mask8; const int* mask32; const int* mflag;
  unsigned short* h1rot; unsigned short* h2rot; unsigned short* ctxrot;
  const unsigned short* zbuf;
  float* c1; float* c2;
  float* aw; float* awc; float* eP; unsigned short* locTh;
  unsigned* arrive; unsigned* root; unsigned* release;
  float* outp; float* wout;
};

__global__ void __launch_bounds__(NT) scan_kernel(SArgs a){
  extern __shared__ char dynsm[];
  unsigned short* Lw1 = (unsigned short*)dynsm;             // 28672
  unsigned short* Lw2 = (unsigned short*)(dynsm + 57344);   // 40960
  float* gsc1 = (float*)(dynsm + 139264);                   // [64][17]
  float* gsc2 = (float*)(dynsm + 143616);                   // [64][17]
  float* sA   = (float*)(dynsm + 147968);                   // [2560]
  float* sq   = (float*)(dynsm + 158208);                   // [32]
  float* sv   = (float*)(dynsm + 158336);                   // [32]
  float* red  = (float*)(dynsm + 158464);                   // [8]

  const int beta = ((blockIdx.x & 7) << 5) | (blockIdx.x >> 3);  // XCD-chunked
  const int grp  = blockIdx.x & 7;
  const int tid = threadIdx.x;
  const int wav = tid>>6;
  const int lan = tid&63;

  const int cc  = lan>>4;
  const int b4  = beta>>2;
  const int q4  = beta&3;
  unsigned ph = 0;

  {
    const short8* g1 = (const short8*)(a.Wp1h + (size_t)beta*28672);
    short8* l1 = (short8*)Lw1;
    for (int i=tid; i<3584; i+=NT) l1[i] = g1[i];
    const short8* g2 = (const short8*)(a.Wp2h + (size_t)beta*40960);
    short8* l2 = (short8*)Lw2;
    for (int i=tid; i<5120; i+=NT) l2[i] = g2[i];
  }

  bool mv = false;
  if (tid<256) mv = (a.mflag[0] ? (a.mask32[b4*256+tid] != 0) : (a.mask8[b4*256+tid] != 0));
  __syncthreads();

  for (int tau=0; tau<=400; ++tau){
    const unsigned short* h1p = (tau==0)? a.zbuf : a.h1rot + (size_t)(tau-1)*65536;
    const unsigned short* h2p = (tau<=1)? a.zbuf : a.h2rot + (size_t)(tau-2)*65536;
    const unsigned short* cxp = (tau==0)? a.zbuf : a.ctxrot + (size_t)(tau-1)*32768;
    unsigned short* h1w = a.h1rot + (size_t)tau*65536;
    unsigned short* h2w = a.h2rot + (size_t)(tau>0 ? tau-1 : 0)*65536;
    unsigned short* cxw = a.ctxrot + (size_t)tau*32768;

    // ================= Phase A: LSTM1 (waves 0-3) ∥ LSTM2 (waves 4-7) =================
    if (tau<400 && wav<4){
      const int row = wav*16 + (lan&15);
      f32x4 A0={0.f,0.f,0.f,0.f};
      const unsigned short* wh = Lw1 + lan*8;
      {
        const unsigned short* xh = a.xbh + ((size_t)tau*64 + row)*256 + cc*8;
        #pragma unroll
        for(int kt=0;kt<8;kt++)
          A0=mfma16(*(const short8*)(xh+kt*32), *(const short8*)(wh+kt*512), A0);
      }
      {
        const unsigned short* xh = cxp + row*512 + cc*8;
        #pragma unroll 8
        for(int kt=8;kt<24;kt++)
          A0=mfma16(*(const short8*)(xh+(kt-8)*32), *(const short8*)(wh+kt*512), A0);
      }
      {
        const unsigned short* xh = h1p + row*1024 + cc*8;
        #pragma unroll 8
        for(int kt=24;kt<56;kt++)
          A0=mfma16(*(const short8*)(xh+(kt-24)*32), *(const short8*)(wh+kt*512), A0);
      }
      #pragma unroll
      for(int r=0;r<4;r++) gsc1[(wav*16 + cc*4 + r)*17 + (lan&15)] = A0[r];
    }
    if (tau>0 && wav>=4){
      const int wv2 = wav-4;
      const int row = wv2*16 + (lan&15);
      f32x4 A0={0.f,0.f,0.f,0.f};
      const unsigned short* wh = Lw2 + lan*8;
      {
        const unsigned short* xh = h1p + row*1024 + cc*8;
        #pragma unroll 8
        for(int kt=0;kt<32;kt++)
          A0=mfma16(*(const short8*)(xh+kt*32), *(const short8*)(wh+kt*512), A0);
      }
      {
        const unsigned short* xh = cxp + row*512 + cc*8;
        #pragma unroll 8
        for(int kt=32;kt<48;kt++)
          A0=mfma16(*(const short8*)(xh+(kt-32)*32), *(const short8*)(wh+kt*512), A0);
      }
      {
        const unsigned short* xh = h2p + row*1024 + cc*8;
        #pragma unroll 8
        for(int kt=48;kt<80;kt++)
          A0=mfma16(*(const short8*)(xh+(kt-48)*32), *(const short8*)(wh+kt*512), A0);
      }
      #pragma unroll
      for(int r=0;r<4;r++) gsc2[(wv2*16 + cc*4 + r)*17 + (lan&15)] = A0[r];
    }
    __syncthreads();
    if (tau<400 && tid<256){
      int m = tid>>2, j = tid&3, u = beta*4+j;
      float gi = gsc1[m*17+0+j]  + a.bsum1[0*1024+u];
      float gf = gsc1[m*17+4+j]  + a.bsum1[1*1024+u];
      float gg = gsc1[m*17+8+j]  + a.bsum1[2*1024+u];
      float go = gsc1[m*17+12+j] + a.bsum1[3*1024+u];
      float cp = a.c1[m*1024+u];
      float cn = sigm(gf)*cp + sigm(gi)*tanh_(gg);
      a.c1[m*1024+u] = cn;
      float hn = sigm(go)*tanh_(cn);
      sth(h1w + m*1024 + u, f2b(hn));
    }
    if (tau>0 && tid>=256){
      int t2 = tid-256;
      int m = t2>>2, j = t2&3, u = beta*4+j;
      float gi = gsc2[m*17+0+j]  + a.bsum2[0*1024+u];
      float gf = gsc2[m*17+4+j]  + a.bsum2[1*1024+u];
      float gg = gsc2[m*17+8+j]  + a.bsum2[2*1024+u];
      float go = gsc2[m*17+12+j] + a.bsum2[3*1024+u];
      float cp = a.c2[m*1024+u];
      float cn = sigm(gf)*cp + sigm(gi)*tanh_(gg);
      a.c2[m*1024+u] = cn;
      float hn = sigm(go)*tanh_(cn);
      sth(h2w + m*1024 + u, f2b(hn));
    }
    if (tau<400){
      if (tid<128){
        float2 v = ld2f(a.aw + b4*256 + tid*2);
        sA[tid*2]=v.x; sA[tid*2+1]=v.y;
        float2 w2 = ld2f(a.awc + b4*256 + tid*2);
        sA[256+tid*2]=w2.x; sA[257+tid*2]=w2.y;
      }
      for(int i=tid;i<1984;i+=NT) sA[512+i] = a.loc_conv[i];
    }
    __syncthreads();
    if (tau<400){
      const int t0 = q4*64;
      #pragma unroll
      for(int jj=0;jj<4;jj++){
        int o = tid*4+jj;
        int f = o>>6, tl = o&63, t = t0+tl;
        float s = 0.f;
        #pragma unroll
        for(int c=0;c<2;c++){
          const float* kw = &sA[512 + (f*2+c)*31];
          const float* wv = &sA[c*256];
          for(int k=0;k<31;k++){
            int tt = t + k - 15;
            if (tt>=0 && tt<256) s += wv[tt]*kw[k];
          }
        }
        sth(a.locTh + (size_t)b4*8192 + f*256 + t, f2b(s));
      }
    }
    gbar2(a.arrive, a.root, a.release, grp, ph);
    // ================= Phase B: q/e path (tid<256) ∥ out-proj (tid 256-415) =================
    if (tau<400 && tid<256){
      const unsigned short* h1c = a.h1rot + (size_t)tau*65536 + b4*1024;
      for(int i=tid;i<1024;i+=256) sA[i] = b2f(h1c[i]);
    }
    if (tau>0 && tid>=256){
      int t2 = tid-256;
      const unsigned short* h2c = a.h2rot + (size_t)(tau-1)*65536 + b4*1024;
      const unsigned short* cxc = a.ctxrot + (size_t)(tau-1)*32768 + b4*512;
      for(int i=t2;i<1024;i+=256) sA[1024+i] = b2f(h2c[i]);
      for(int i=t2;i<512;i+=256)  sA[2048+i] = b2f(cxc[i]);
    }
    __syncthreads();
    if (tau<400 && tid<256){
      int ml = tid>>3, sg = tid&7;
      const unsigned short* wq = a.WqH + (size_t)(q4*32+ml)*1024;
      float s=0.f;
      #pragma unroll 8
      for(int i=0;i<128;i++) s += sA[sg + i*8]*b2f(wq[sg + i*8]);
      s += __shfl_xor(s,1); s += __shfl_xor(s,2); s += __shfl_xor(s,4);
      if (sg==0) sq[ml] = s;
    }
    if (tau>0 && tid>=256 && tid<416){
      int t2 = tid-256;
      int nl = t2>>3, sg = t2&7, nm = q4*20+nl;
      const unsigned short* wo = a.WoutH + (size_t)nm*1536;
      float s=0.f;
      #pragma unroll 8
      for(int i=0;i<192;i++) s += sA[1024 + sg + i*8]*b2f(wo[sg + i*8]);
      s += __shfl_xor(s,1); s += __shfl_xor(s,2); s += __shfl_xor(s,4);
      if (sg==0) a.outp[(size_t)b4*32000 + nm*400 + (tau-1)] = s + a.bout[nm];
    }
    __syncthreads();
    if (tau<400 && tid<256){
      for(int i=tid;i<1024;i+=256) sA[i] = a.Wloc[(q4*32 + (i>>5))*32 + (i&31)];
    }
    if (tid<32) sv[tid] = a.v_att[q4*32+tid];
    __syncthreads();
    if (tau<400 && tid<256){
      int t = tid;
      float lc[32];
      const unsigned short* lb = a.locTh + (size_t)b4*8192 + t;
      #pragma unroll
      for(int f=0;f<32;f++) lc[f] = b2f(ldh(lb + f*256));
      const unsigned short* kb = a.keypT + ((size_t)b4*128 + q4*32)*256 + t;
      float acc=0.f;
      for(int mm=0;mm<32;mm++){
        float lf=0.f;
        #pragma unroll
        for(int f=0;f<32;f++) lf += lc[f]*sA[mm*32+f];
        acc += tanh_(sq[mm] + b2f(kb[mm*256]) + lf)*sv[mm];
      }
      stf(a.eP + b4*1024 + t*4 + q4, acc);
    }
    if (tau==400) break;
    gbar2(a.arrive, a.root, a.release, grp, ph);
    // ================= Phase C =================
    {
      float e=0.f, pe=0.f, mx=0.f;
      if (tid<256){
        const float* ep = a.eP + b4*1024 + tid*4;
        e = ldf(ep+0)+ldf(ep+1)+ldf(ep+2)+ldf(ep+3);
        if (!mv) e = -1e9f;
        mx = e;
        #pragma unroll
        for(int off=1;off<64;off<<=1) mx = fmaxf(mx, __shfl_xor(mx,off));
        if (lan==0) red[wav] = mx;
      }
      __syncthreads();
      if (tid<256){
        mx = fmaxf(fmaxf(red[0],red[1]), fmaxf(red[2],red[3]));
        pe = __expf(e-mx);
        float sm = pe;
        #pragma unroll
        for(int off=1;off<64;off<<=1) sm += __shfl_xor(sm,off);
        if (lan==0) red[4+wav] = sm;
      }
      __syncthreads();
      if (tid<256){
        float sm = red[4]+red[5]+red[6]+red[7];
        float awt = pe/sm;
        if (q4==0){
          stf(a.aw + b4*256+tid, awt);
          stf(a.awc + b4*256+tid, ldf(a.awc + b4*256+tid) + awt);
          a.wout[(size_t)b4*102400 + (size_t)tid*400 + tau] = awt;
        }
        sA[tid] = awt;
      }
      __syncthreads();
      {
        int fl = tid&127, th = tid>>7;
        const unsigned short* xp = a.xinh + ((size_t)(b4*256 + th*64))*512 + q4*128 + fl;
        float s=0.f;
        for(int i=0;i<64;i++) s += sA[th*64+i]*b2f(xp[(size_t)i*512]);
        sA[256+tid] = s;
      }
      __syncthreads();
      if (tid<128){
        float v = sA[256+tid] + sA[384+tid] + sA[512+tid] + sA[640+tid];
        sth(cxw + b4*512 + q4*128 + tid, f2b(v));
      }
    }
    gbar2(a.arrive, a.root, a.release, grp, ph);
  }
}

extern "C" void kernel_launch(void* const* d_in, const int* in_sizes, int n_in,
                              void* d_out, int out_size, void* d_ws, size_t ws_size,
                              hipStream_t stream){
  (void)in_sizes; (void)n_in; (void)out_size; (void)ws_size;
  const float* xin   = (const float*)d_in[0];
  const float* target= (const float*)d_in[2];
  const float* Wpre1 = (const float*)d_in[3];
  const float* bpre1 = (const float*)d_in[4];
  const float* Wpre2 = (const float*)d_in[5];
  const float* bpre2 = (const float*)d_in[6];
  const float* Wq    = (const float*)d_in[7];
  const float* Wk    = (const float*)d_in[8];
  const float* loc_conv = (const float*)d_in[9];
  const float* Wloc  = (const float*)d_in[10];
  const float* v_att = (const float*)d_in[11];
  const float* Wih1  = (const float*)d_in[12];
  const float* Whh1  = (const float*)d_in[13];
  const float* bih1  = (const float*)d_in[14];
  const float* bhh1  = (const float*)d_in[15];
  const float* Wih2  = (const float*)d_in[16];
  const float* Whh2  = (const float*)d_in[17];
  const float* bih2  = (const float*)d_in[18];
  const float* bhh2  = (const float*)d_in[19];
  const float* Wout  = (const float*)d_in[20];
  const float* boutp = (const float*)d_in[21];

  char* w = (char*)d_ws;
  auto carve=[&](size_t bytes)->void*{ void* r=(void*)w; w += (bytes+255)&~(size_t)255; return r; };
  // state region (zeroed every launch) — must stay first & contiguous
  unsigned short* zbuf = (unsigned short*)carve((size_t)64*1024*2);
  float* c1  = (float*)carve((size_t)64*1024*4);
  float* c2  = (float*)carve((size_t)64*1024*4);
  float* aw  = (float*)carve((size_t)64*256*4);
  float* awc = (float*)carve((size_t)64*256*4);
  unsigned* arrive  = (unsigned*)carve(1024);
  unsigned* rootc   = (unsigned*)carve(256);
  unsigned* release = (unsigned*)carve(1024);
  int* mflag = (int*)carve(256);
  size_t state_bytes = (size_t)(w - (char*)d_ws);
  float* eP   = (float*)carve((size_t)64*256*4*4);
  unsigned short* locTh = (unsigned short*)carve((size_t)64*32*256*2);
  unsigned short* keypT = (unsigned short*)carve((size_t)64*128*256*2);
  unsigned short* xinh  = (unsigned short*)carve((size_t)64*256*512*2);
  unsigned short* xbh = (unsigned short*)carve((size_t)400*64*256*2);
  float* bsum1 = (float*)carve((size_t)4096*4);
  float* bsum2 = (float*)carve((size_t)4096*4);
  unsigned short* WqH = (unsigned short*)carve((size_t)128*1024*2);
  unsigned short* WoutH = (unsigned short*)carve((size_t)80*1536*2);
  unsigned short* Wp1h = (unsigned short*)carve((size_t)256*56*512*2);
  unsigned short* Wp2h = (unsigned short*)carve((size_t)256*80*512*2);
  unsigned short* h1rot = (unsigned short*)carve((size_t)400*65536*2);
  unsigned short* h2rot = (unsigned short*)carve((size_t)400*65536*2);
  unsigned short* ctxrot= (unsigned short*)carve((size_t)400*32768*2);

  hipMemsetAsync(d_ws, 0, state_bytes, stream);
  maskdet_k<<<1, 256, 0, stream>>>((const unsigned*)d_in[1], mflag);
  xin2bf_k<<<32768, 256, 0, stream>>>(xin, xinh);
  prenet_k<<<400, 256, 0, stream>>>(target, Wpre1, bpre1, Wpre2, bpre2, xbh);
  keyproj_k<<<1024, 128, 0, stream>>>(xin, Wk, keypT);
  prep_k<<<64, 256, 0, stream>>>(bih1,bhh1,bih2,bhh2,Wq,Wout,bsum1,bsum2,WqH,WoutH);
  perm_k<<<2048, 256, 0, stream>>>(Wih1,Whh1,Wih2,Whh2,Wp1h,Wp2h);

  SArgs a;
  a.loc_conv=loc_conv; a.v_att=v_att; a.bout=boutp;
  a.WqH=WqH; a.WoutH=WoutH; a.Wloc=Wloc;
  a.keypT=keypT; a.xinh=xinh; a.xbh=xbh;
  a.Wp1h=Wp1h; a.Wp2h=Wp2h;
  a.bsum1=bsum1; a.bsum2=bsum2;
  a.mask8=(const unsigned char*)d_in[1]; a.mask32=(const int*)d_in[1]; a.mflag=mflag;
  a.h1rot=h1rot; a.h2rot=h2rot; a.ctxrot=ctxrot; a.zbuf=zbuf;
  a.c1=c1; a.c2=c2;
  a.aw=aw; a.awc=awc; a.eP=eP; a.locTh=locTh;
  a.arrive=arrive; a.root=rootc; a.release=release;
  a.outp=(float*)d_out; a.wout=(float*)d_out + (size_t)64*80*400;

  hipFuncSetAttribute((const void*)scan_kernel, hipFuncAttributeMaxDynamicSharedMemorySize, DYNB);
  scan_kernel<<<dim3(NB), dim3(NT), DYNB, stream>>>(a);
}